// Round 12
// baseline (196.596 us; speedup 1.0000x reference)
//
#include <hip/hip_runtime.h>
#include <cstdint>
#include <cstddef>

// ---------------------------------------------------------------------------
// GCN: 3 layers, shared graph.
//   - Algebra: only layer 1 has ReLU; projection commutes with aggregation:
//       out = log_softmax( A^2 (relu(A xW1 + b1) W23) + s*(b2W3) + b3 ).
//     One 128-dim gather (compulsory L2-fill floor: 82MB @ ~1.7TB/s = 48us,
//     invariant R7-R11), then 10-dim f32 space (2MB, L2-resident).
//   - R11 lesson: fusing GEMM (17KB LDS, 56 VGPR) with fill (latency-bound
//     scatter needing max occupancy) degraded fill 2x. Kernels with opposite
//     resource profiles must NOT share a dispatch. Reverted; kept the wins
//     (fillc eliminated via atomicSub countdown on cnt; wt fused into count).
//   - GEMM1: bf16 MFMA 16x16x32, C via LDS round-trip (16B stores).
// ---------------------------------------------------------------------------

typedef unsigned int uint;
typedef unsigned short u16;
typedef uint  uint4e  __attribute__((ext_vector_type(4)));
typedef float float4e __attribute__((ext_vector_type(4)));
typedef uint  uint2e  __attribute__((ext_vector_type(2)));
typedef int   int2e   __attribute__((ext_vector_type(2)));
typedef int   int4e   __attribute__((ext_vector_type(4)));
using bf16x8 = __attribute__((ext_vector_type(8))) short;
using f32x4  = __attribute__((ext_vector_type(4))) float;

__device__ __forceinline__ float bf_lo(uint v) { return __uint_as_float(v << 16); }
__device__ __forceinline__ float bf_hi(uint v) { return __uint_as_float(v & 0xffff0000u); }
__device__ __forceinline__ u16 bf16_1(float a) {
    uint ua = __float_as_uint(a);
    ua = (ua + 0x7fffu + ((ua >> 16) & 1u)) >> 16;          // RNE
    return (u16)ua;
}
__device__ __forceinline__ uint pack_bf2(float a, float b) {
    return (uint)bf16_1(a) | ((uint)bf16_1(b) << 16);
}

// Blocks [0, NCB): histogram of dst degrees. Block NCB: Wt1 transpose.
// Block NCB+1: W23 = W2@W3, b23 = b2@W3.
__global__ __launch_bounds__(256) void count_wt_kernel(const int* __restrict__ ei, int E,
        int* __restrict__ cnt, const float* __restrict__ W1, const float* __restrict__ W2,
        const float* __restrict__ W3, const float* __restrict__ b2,
        u16* __restrict__ Wt1, float* __restrict__ W23, float* __restrict__ b23, int ncb) {
    int tid = threadIdx.x;
    if ((int)blockIdx.x < ncb) {
        int i = blockIdx.x * 256 + tid;
        int stride = ncb * 256;
        int nG = E >> 2;
        for (int g = i; g < nG; g += stride) {
            int4e d = *reinterpret_cast<const int4e*>(ei + E + g * 4);
            atomicAdd(&cnt[d.x], 1);
            atomicAdd(&cnt[d.y], 1);
            atomicAdd(&cnt[d.z], 1);
            atomicAdd(&cnt[d.w], 1);
        }
        for (int e = nG * 4 + i; e < E; e += stride) atomicAdd(&cnt[ei[E + e]], 1);
    } else if ((int)blockIdx.x == ncb) {
        for (int i = 0; i < 64; ++i) {
            int idx = tid + i * 256;          // 16384 = 128*128
            int k = idx >> 7, c = idx & 127;
            Wt1[c * 128 + k] = bf16_1(W1[idx]);
        }
    } else {
        __shared__ float w3s[1280];
        for (int i = tid; i < 1280; i += 256) w3s[i] = W3[i];
        __syncthreads();
#pragma unroll
        for (int i = 0; i < 5; ++i) {
            int idx = tid * 5 + i;            // 1280 outputs
            int k = idx / 10, c = idx % 10;
            float acc = 0.f;
            for (int j = 0; j < 128; ++j) acc += W2[k * 128 + j] * w3s[j * 10 + c];
            W23[idx] = acc;
        }
        if (tid < 10) {
            float acc = 0.f;
            for (int j = 0; j < 128; ++j) acc += b2[j] * w3s[j * 10 + tid];
            b23[tid] = acc;
        }
    }
}

// Pass 1: per-block (1024 elems) totals; also computes dis = rsqrt(deg+1).
__global__ __launch_bounds__(256) void scan_partial(const int* __restrict__ cnt,
        int* __restrict__ bsum, float* __restrict__ dis, int n) {
    __shared__ int red[256];
    int b = blockIdx.x, tid = threadIdx.x;
    int base = b * 1024 + tid * 4;
    int4 v = make_int4(0, 0, 0, 0);
    if (base + 4 <= n) {
        v = *reinterpret_cast<const int4*>(cnt + base);
    } else {
        if (base + 0 < n) v.x = cnt[base + 0];
        if (base + 1 < n) v.y = cnt[base + 1];
        if (base + 2 < n) v.z = cnt[base + 2];
    }
    if (base + 0 < n) dis[base + 0] = rsqrtf((float)(v.x + 1));
    if (base + 1 < n) dis[base + 1] = rsqrtf((float)(v.y + 1));
    if (base + 2 < n) dis[base + 2] = rsqrtf((float)(v.z + 1));
    if (base + 3 < n) dis[base + 3] = rsqrtf((float)(v.w + 1));
    red[tid] = v.x + v.y + v.z + v.w;
    __syncthreads();
    for (int d = 128; d > 0; d >>= 1) {
        if (tid < d) red[tid] += red[tid + d];
        __syncthreads();
    }
    if (tid == 0) bsum[b] = red[0];
}

// Pass 2: wave 0 redundantly scans block sums for this block's offset, then
// block-local exclusive scan + offset -> row_ptr.
__global__ __launch_bounds__(256) void scan_final(const int* __restrict__ cnt,
        const int* __restrict__ bsum, int* __restrict__ row_ptr, int nb, int n) {
    __shared__ int red[256];
    __shared__ int sh_boff;
    int b = blockIdx.x, tid = threadIdx.x;
    if (tid < 64) {
        int s = (tid < nb) ? bsum[tid] : 0;
        int v = s;
        for (int d = 1; d < 64; d <<= 1) {
            int t = __shfl_up(v, d);
            if (tid >= d) v += t;
        }
        if (tid == b) sh_boff = v - s;                 // exclusive offset of this block
        if (b == 0 && tid == 63) row_ptr[n] = v;       // grand total
    }
    int base = b * 1024 + tid * 4;
    int4 v = make_int4(0, 0, 0, 0);
    if (base + 4 <= n) {
        v = *reinterpret_cast<const int4*>(cnt + base);
    } else {
        if (base + 0 < n) v.x = cnt[base + 0];
        if (base + 1 < n) v.y = cnt[base + 1];
        if (base + 2 < n) v.z = cnt[base + 2];
    }
    int s = v.x + v.y + v.z + v.w;
    red[tid] = s;
    __syncthreads();
    for (int d = 1; d < 256; d <<= 1) {
        int t = (tid >= d) ? red[tid - d] : 0;
        __syncthreads();
        red[tid] += t;
        __syncthreads();
    }
    int off = sh_boff + red[tid] - s;
    if (base + 0 < n) { row_ptr[base + 0] = off; off += v.x; }
    if (base + 1 < n) { row_ptr[base + 1] = off; off += v.y; }
    if (base + 2 < n) { row_ptr[base + 2] = off; off += v.z; }
    if (base + 3 < n) { row_ptr[base + 3] = off; }
}

// CSR fill, counting DOWN on cnt (deg -> 0): slot = atomicSub(cnt[d])-1.
__global__ __launch_bounds__(256) void fill_kernel(const int* __restrict__ ei, int E,
        const int* __restrict__ row_ptr, int* __restrict__ cnt,
        const float* __restrict__ dis, int2e* __restrict__ esort) {
    int i = blockIdx.x * blockDim.x + threadIdx.x;
    int stride = gridDim.x * blockDim.x;
    int nG = E >> 2;
    for (int g = i; g < nG; g += stride) {
        int4e s4 = *reinterpret_cast<const int4e*>(ei + g * 4);
        int4e d4 = *reinterpret_cast<const int4e*>(ei + E + g * 4);
#pragma unroll
        for (int k = 0; k < 4; ++k) {
            int s = k == 0 ? s4.x : k == 1 ? s4.y : k == 2 ? s4.z : s4.w;
            int d = k == 0 ? d4.x : k == 1 ? d4.y : k == 2 ? d4.z : d4.w;
            int pos = row_ptr[d] + atomicSub(&cnt[d], 1) - 1;
            int2e pkt;
            pkt.x = s;
            pkt.y = __float_as_int(dis[s] * dis[d]);
            esort[pos] = pkt;
        }
    }
    for (int e = nG * 4 + i; e < E; e += stride) {
        int s = ei[e];
        int d = ei[E + e];
        int pos = row_ptr[d] + atomicSub(&cnt[d], 1) - 1;
        int2e pkt;
        pkt.x = s;
        pkt.y = __float_as_int(dis[s] * dis[d]);
        esort[pos] = pkt;
    }
}

// out u16[n][128] = bf16( A[n][128] @ W ),  W given as Wt bf16 [col][k].
// C is written via LDS round-trip -> fully coalesced 16B stores.
__global__ __launch_bounds__(256) void gemm_mfma(const float* __restrict__ A,
        const u16* __restrict__ Wt, u16* __restrict__ out, int n) {
    constexpr int LDA = 136;                 // 128 + 8 pad (bf16) -> 2-way LDS only
    __shared__ u16 as[64 * LDA];
    int tid = threadIdx.x;
    int wave = tid >> 6, lane = tid & 63;
    int row0 = blockIdx.x * 64;
    int l16 = lane & 15;
    int krow = (lane >> 4) * 8;              // k-octet within 32-wide K block

#pragma unroll
    for (int i = 0; i < 8; ++i) {
        int idx = tid + i * 256;             // 2048 quads of 4 f32
        int r = idx >> 5;
        int q = (idx & 31) * 4;
        float4e v = {0.f, 0.f, 0.f, 0.f};
        if (row0 + r < n)
            v = *reinterpret_cast<const float4e*>(A + (size_t)(row0 + r) * 128 + q);
        uint2e p;
        p.x = pack_bf2(v.x, v.y);
        p.y = pack_bf2(v.z, v.w);
        *reinterpret_cast<uint2e*>(&as[r * LDA + q]) = p;
    }

    bf16x8 b[2][4];
#pragma unroll
    for (int n2 = 0; n2 < 2; ++n2)
#pragma unroll
        for (int kb = 0; kb < 4; ++kb)
            b[n2][kb] = *reinterpret_cast<const bf16x8*>(
                Wt + (size_t)(wave * 32 + n2 * 16 + l16) * 128 + kb * 32 + krow);

    __syncthreads();

    f32x4 acc[4][2] = {};
#pragma unroll
    for (int m = 0; m < 4; ++m) {
#pragma unroll
        for (int kb = 0; kb < 4; ++kb) {
            bf16x8 a = *reinterpret_cast<const bf16x8*>(
                &as[(m * 16 + l16) * LDA + kb * 32 + krow]);
#pragma unroll
            for (int n2 = 0; n2 < 2; ++n2)
                acc[m][n2] = __builtin_amdgcn_mfma_f32_16x16x32_bf16(a, b[n2][kb], acc[m][n2], 0, 0, 0);
        }
    }

    __syncthreads();                         // as[] reuse as C-staging
    u16* cs = as;
#pragma unroll
    for (int m = 0; m < 4; ++m) {
        int rb = m * 16 + (lane >> 4) * 4;
#pragma unroll
        for (int n2 = 0; n2 < 2; ++n2) {
            int col = wave * 32 + n2 * 16 + l16;
#pragma unroll
            for (int r = 0; r < 4; ++r)
                cs[(rb + r) * 128 + col] = bf16_1(acc[m][n2][r]);
        }
    }
    __syncthreads();
#pragma unroll
    for (int i = 0; i < 4; ++i) {
        int idx = tid + i * 256;             // 1024 octs: row=idx>>4, oct=(idx&15)
        int r = idx >> 4;
        int q = (idx & 15) * 8;
        if (row0 + r < n)
            *reinterpret_cast<uint4e*>(out + (size_t)(row0 + r) * 128 + q) =
                *reinterpret_cast<const uint4e*>(&cs[r * 128 + q]);
    }
}

// Full-wave gather: lane owns dims 2*lane..2*lane+1, 8 edges in flight.
__device__ __forceinline__ void gather_accum(const uint* __restrict__ xw,
        const int2e* __restrict__ esort, const float* __restrict__ dis,
        int v, int lane, int beg, int end, float& ax, float& ay) {
    int e = beg;
    for (; e + 7 < end; e += 8) {
        int2e ed[8];
        uint vv[8];
#pragma unroll
        for (int j = 0; j < 8; ++j) ed[j] = esort[e + j];
#pragma unroll
        for (int j = 0; j < 8; ++j) vv[j] = xw[(size_t)ed[j].x * 64 + lane];
#pragma unroll
        for (int j = 0; j < 8; ++j) {
            float w = __int_as_float(ed[j].y);
            ax += w * bf_lo(vv[j]);
            ay += w * bf_hi(vv[j]);
        }
    }
    for (; e + 1 < end; e += 2) {
        int2e e0 = esort[e];
        int2e e1 = esort[e + 1];
        uint v0 = xw[(size_t)e0.x * 64 + lane];
        uint v1 = xw[(size_t)e1.x * 64 + lane];
        float w0 = __int_as_float(e0.y), w1 = __int_as_float(e1.y);
        ax += w0 * bf_lo(v0); ay += w0 * bf_hi(v0);
        ax += w1 * bf_lo(v1); ay += w1 * bf_hi(v1);
    }
    if (e < end) {
        int2e e0 = esort[e];
        uint v0 = xw[(size_t)e0.x * 64 + lane];
        float w0 = __int_as_float(e0.y);
        ax += w0 * bf_lo(v0); ay += w0 * bf_hi(v0);
    }
    float dv = dis[v];
    float wv = dv * dv;                            // self-loop norm
    uint vs = xw[(size_t)v * 64 + lane];
    ax += wv * bf_lo(vs); ay += wv * bf_hi(vs);
}

// Pass A: z[v][0..9] = relu(Agg(x@W1)[v] + b1) @ W23   (the one big gather).
__global__ __launch_bounds__(256) void agg_proj_kernel(const uint* __restrict__ xw,
        const int* __restrict__ row_ptr, const int2e* __restrict__ esort,
        const float* __restrict__ dis, const float* __restrict__ b1,
        const float* __restrict__ W23, float* __restrict__ z, int n) {
    int v = (int)((blockIdx.x * blockDim.x + threadIdx.x) >> 6);
    int lane = threadIdx.x & 63;
    if (v >= n) return;
    float ax = 0.f, ay = 0.f;
    gather_accum(xw, esort, dis, v, lane, row_ptr[v], row_ptr[v + 1], ax, ay);
    ax = fmaxf(ax + b1[lane * 2], 0.f);
    ay = fmaxf(ay + b1[lane * 2 + 1], 0.f);
    const float* w0 = W23 + (size_t)lane * 20;     // this lane's 2 rows of W23
    float p[10];
#pragma unroll
    for (int c = 0; c < 10; ++c) p[c] = ax * w0[c] + ay * w0[10 + c];
#pragma unroll
    for (int c = 0; c < 10; ++c) {
#pragma unroll
        for (int d = 1; d < 64; d <<= 1) p[c] += __shfl_xor(p[c], d);
    }
    if (lane < 10) z[(size_t)v * 10 + lane] = p[lane];
}

// Pass B/C: 10-dim aggregation, 4 nodes per wave (16-lane groups, lanes 0-9
// of each group carry dims). FINAL=0: zout = Agg(zin).
// FINAL=1: out = log_softmax(Agg(zin) + s*b23 + b3).
template <int FINAL>
__global__ __launch_bounds__(256) void agg10_kernel(const float* __restrict__ zin,
        const int* __restrict__ row_ptr, const int2e* __restrict__ esort,
        const float* __restrict__ dis, const float* __restrict__ b23,
        const float* __restrict__ b3, float* __restrict__ zout, int n) {
    int wid = (int)((blockIdx.x * blockDim.x + threadIdx.x) >> 6);
    int lane = threadIdx.x & 63;
    int grp = lane >> 4, gl = lane & 15;
    int v = wid * 4 + grp;
    bool act = (v < n);
    bool dl = (gl < 10);
    int beg = act ? row_ptr[v] : 0;
    int end = act ? row_ptr[v + 1] : 0;
    float acc = 0.f, sw = 0.f;
    int e = beg;
    for (; e + 3 < end; e += 4) {
        int2e e0 = esort[e], e1 = esort[e + 1], e2 = esort[e + 2], e3 = esort[e + 3];
        float z0 = dl ? zin[(size_t)e0.x * 10 + gl] : 0.f;
        float z1 = dl ? zin[(size_t)e1.x * 10 + gl] : 0.f;
        float z2 = dl ? zin[(size_t)e2.x * 10 + gl] : 0.f;
        float z3 = dl ? zin[(size_t)e3.x * 10 + gl] : 0.f;
        float w0 = __int_as_float(e0.y), w1 = __int_as_float(e1.y);
        float w2 = __int_as_float(e2.y), w3 = __int_as_float(e3.y);
        acc += w0 * z0 + w1 * z1 + w2 * z2 + w3 * z3;
        sw += (w0 + w1) + (w2 + w3);
    }
    for (; e < end; ++e) {
        int2e e0 = esort[e];
        float z0 = dl ? zin[(size_t)e0.x * 10 + gl] : 0.f;
        float w0 = __int_as_float(e0.y);
        acc += w0 * z0;
        sw += w0;
    }
    if (act) {
        float dv = dis[v];
        float wv = dv * dv;                        // self-loop
        float zs = dl ? zin[(size_t)v * 10 + gl] : 0.f;
        acc += wv * zs;
        sw += wv;
    }
    if (FINAL == 0) {
        if (act && dl) zout[(size_t)v * 10 + gl] = acc;
    } else {
        float p = acc + (dl ? sw * b23[gl] + b3[gl] : 0.f);
        float m = dl ? p : -3.4e38f;
#pragma unroll
        for (int mask = 1; mask < 16; mask <<= 1) m = fmaxf(m, __shfl_xor(m, mask));
        float s = dl ? __expf(p - m) : 0.f;
#pragma unroll
        for (int mask = 1; mask < 16; mask <<= 1) s += __shfl_xor(s, mask);
        float ls = __logf(s);
        if (act && dl) zout[(size_t)v * 10 + gl] = p - m - ls;
    }
}

extern "C" void kernel_launch(void* const* d_in, const int* in_sizes, int n_in,
                              void* d_out, int out_size, void* d_ws, size_t ws_size,
                              hipStream_t stream) {
    const float* x  = (const float*)d_in[0];
    const int*   ei = (const int*)d_in[1];   // [2][E] int32
    const float* W1 = (const float*)d_in[2];
    const float* b1 = (const float*)d_in[3];
    const float* W2 = (const float*)d_in[4];
    const float* b2 = (const float*)d_in[5];
    const float* W3 = (const float*)d_in[6];
    const float* b3 = (const float*)d_in[7];
    int N = in_sizes[0] / 128;
    int E = in_sizes[1] / 2;
    int NB = (N + 1023) / 1024;   // 49 for N=50000 (must be <= 64)

    char* ws = (char*)d_ws;
    size_t off = 0;
    auto alloc = [&](size_t bytes) -> char* {
        char* p = ws + off;
        off = (off + bytes + 255) & ~(size_t)255;
        return p;
    };
    int*   cnt     = (int*)alloc((size_t)N * 4);
    int*   row_ptr = (int*)alloc(((size_t)N + 1) * 4);
    float* dis     = (float*)alloc((size_t)N * 4);
    int*   bsum    = (int*)alloc(64 * 4);
    u16*   Wt1     = (u16*)alloc(128 * 128 * 2);
    float* W23     = (float*)alloc(128 * 10 * 4);
    float* b23     = (float*)alloc(10 * 4);
    int2e* esort   = (int2e*)alloc((size_t)E * 8);
    uint*  bufA    = (uint*)alloc((size_t)N * 64 * 4);   // bf16x2 packed x@W1
    float* z       = (float*)alloc((size_t)N * 10 * 4);  // h1@W23  (2MB, L2-fits)
    float* z2      = (float*)alloc((size_t)N * 10 * 4);  // Agg(z)

    (void)hipMemsetAsync(cnt, 0, (size_t)N * 4, stream);

    const int NCB = 1024;          // counting blocks

    // --- preprocessing: degree histogram + weight prep (fused) ---
    count_wt_kernel<<<NCB + 2, 256, 0, stream>>>(ei, E, cnt, W1, W2, W3, b2,
                                                 Wt1, W23, b23, NCB);
    // --- layer-1 GEMM (independent of scan/fill; needs Wt1 only) ---
    gemm_mfma<<<(N + 63) / 64, 256, 0, stream>>>(x, Wt1, (u16*)bufA, N);
    scan_partial<<<NB, 256, 0, stream>>>(cnt, bsum, dis, N);
    scan_final<<<NB, 256, 0, stream>>>(cnt, bsum, row_ptr, NB, N);
    fill_kernel<<<1024, 256, 0, stream>>>(ei, E, row_ptr, cnt, dis, esort);
    // --- the single 128-dim gather, fused with ReLU+projection ---
    agg_proj_kernel<<<(N + 3) / 4, 256, 0, stream>>>(bufA, row_ptr, esort, dis, b1, W23, z, N);
    // --- layers 2+3: two 10-dim aggregations (L2-resident table) ---
    agg10_kernel<0><<<(N + 15) / 16, 256, 0, stream>>>(z, row_ptr, esort, dis, nullptr, nullptr, z2, N);
    agg10_kernel<1><<<(N + 15) / 16, 256, 0, stream>>>(z2, row_ptr, esort, dis, b23, b3, (float*)d_out, N);
}

// Round 13
// 186.798 us; speedup vs baseline: 1.0525x; 1.0525x over previous
//
#include <hip/hip_runtime.h>
#include <cstdint>
#include <cstddef>

// ---------------------------------------------------------------------------
// GCN: 3 layers, shared graph.
//   - Algebra: only layer 1 has ReLU; projection commutes with aggregation:
//       out = log_softmax( A^2 (relu(A xW1 + b1) W23) + s*(b2W3) + b3 ).
//     One 128-dim gather (compulsory L2-fill floor: 82MB @ ~1.7TB/s = 48us,
//     invariant R7-R11), then 10-dim f32 space (2MB, L2-resident).
//   - R12 lesson: 800k atomics on 50k counters = ~250 atomics/cache-line;
//     cross-XCD same-line atomics serialize (count was 53us at 0.2% VALU).
//     FIX: 8-way privatized histogram cnt8[c][N], c = blockIdx&7. scan_final
//     converts counts -> per-copy CURSORS in place, so fill also gets /8
//     contention (row order permuted; sums are order-agnostic).
//   - R11 lesson: don't fuse kernels with opposite resource profiles.
//   - GEMM1: bf16 MFMA 16x16x32, C via LDS round-trip (16B stores).
// ---------------------------------------------------------------------------

typedef unsigned int uint;
typedef unsigned short u16;
typedef uint  uint4e  __attribute__((ext_vector_type(4)));
typedef float float4e __attribute__((ext_vector_type(4)));
typedef uint  uint2e  __attribute__((ext_vector_type(2)));
typedef int   int2e   __attribute__((ext_vector_type(2)));
typedef int   int4e   __attribute__((ext_vector_type(4)));
using bf16x8 = __attribute__((ext_vector_type(8))) short;
using f32x4  = __attribute__((ext_vector_type(4))) float;

__device__ __forceinline__ float bf_lo(uint v) { return __uint_as_float(v << 16); }
__device__ __forceinline__ float bf_hi(uint v) { return __uint_as_float(v & 0xffff0000u); }
__device__ __forceinline__ u16 bf16_1(float a) {
    uint ua = __float_as_uint(a);
    ua = (ua + 0x7fffu + ((ua >> 16) & 1u)) >> 16;          // RNE
    return (u16)ua;
}
__device__ __forceinline__ uint pack_bf2(float a, float b) {
    return (uint)bf16_1(a) | ((uint)bf16_1(b) << 16);
}

// Blocks [0, NCB): privatized histogram (copy = blockIdx&7).
// Block NCB: Wt1 transpose. Block NCB+1: W23 = W2@W3, b23 = b2@W3.
__global__ __launch_bounds__(256) void count_wt_kernel(const int* __restrict__ ei, int E,
        int* __restrict__ cnt8, int npl, const float* __restrict__ W1,
        const float* __restrict__ W2, const float* __restrict__ W3,
        const float* __restrict__ b2,
        u16* __restrict__ Wt1, float* __restrict__ W23, float* __restrict__ b23, int ncb) {
    int tid = threadIdx.x;
    if ((int)blockIdx.x < ncb) {
        int* mycnt = cnt8 + (size_t)(blockIdx.x & 7) * npl;
        int i = blockIdx.x * 256 + tid;
        int stride = ncb * 256;
        int nG = E >> 2;
        for (int g = i; g < nG; g += stride) {
            int4e d = *reinterpret_cast<const int4e*>(ei + E + g * 4);
            atomicAdd(&mycnt[d.x], 1);
            atomicAdd(&mycnt[d.y], 1);
            atomicAdd(&mycnt[d.z], 1);
            atomicAdd(&mycnt[d.w], 1);
        }
        for (int e = nG * 4 + i; e < E; e += stride) atomicAdd(&mycnt[ei[E + e]], 1);
    } else if ((int)blockIdx.x == ncb) {
        for (int i = 0; i < 64; ++i) {
            int idx = tid + i * 256;          // 16384 = 128*128
            int k = idx >> 7, c = idx & 127;
            Wt1[c * 128 + k] = bf16_1(W1[idx]);
        }
    } else {
        __shared__ float w3s[1280];
        for (int i = tid; i < 1280; i += 256) w3s[i] = W3[i];
        __syncthreads();
#pragma unroll
        for (int i = 0; i < 5; ++i) {
            int idx = tid * 5 + i;            // 1280 outputs
            int k = idx / 10, c = idx % 10;
            float acc = 0.f;
            for (int j = 0; j < 128; ++j) acc += W2[k * 128 + j] * w3s[j * 10 + c];
            W23[idx] = acc;
        }
        if (tid < 10) {
            float acc = 0.f;
            for (int j = 0; j < 128; ++j) acc += b2[j] * w3s[j * 10 + tid];
            b23[tid] = acc;
        }
    }
}

// Pass 1: per-block (1024 elems) totals over the 8 planes; dis = rsqrt(deg+1).
// Planes are padded to npl (= NB*1024) and zero-initialized -> unguarded int4.
__global__ __launch_bounds__(256) void scan_partial(const int* __restrict__ cnt8, int npl,
        int* __restrict__ bsum, float* __restrict__ dis, int n) {
    __shared__ int red[256];
    int b = blockIdx.x, tid = threadIdx.x;
    int base = b * 1024 + tid * 4;
    int4e v = {0, 0, 0, 0};
#pragma unroll
    for (int c = 0; c < 8; ++c) {
        int4e t = *reinterpret_cast<const int4e*>(cnt8 + (size_t)c * npl + base);
        v.x += t.x; v.y += t.y; v.z += t.z; v.w += t.w;
    }
    if (base + 0 < n) dis[base + 0] = rsqrtf((float)(v.x + 1));
    if (base + 1 < n) dis[base + 1] = rsqrtf((float)(v.y + 1));
    if (base + 2 < n) dis[base + 2] = rsqrtf((float)(v.z + 1));
    if (base + 3 < n) dis[base + 3] = rsqrtf((float)(v.w + 1));
    red[tid] = v.x + v.y + v.z + v.w;
    __syncthreads();
    for (int d = 128; d > 0; d >>= 1) {
        if (tid < d) red[tid] += red[tid + d];
        __syncthreads();
    }
    if (tid == 0) bsum[b] = red[0];
}

// Pass 2: block offset via redundant wave scan; block-local exclusive scan ->
// row_ptr; convert cnt8 planes IN PLACE to per-copy cursors:
//   cnt8[c][d] = row_ptr[d] + sum_{c'<c} cnt8[c'][d].
__global__ __launch_bounds__(256) void scan_final(int* __restrict__ cnt8, int npl,
        const int* __restrict__ bsum, int* __restrict__ row_ptr, int nb, int n) {
    __shared__ int red[256];
    __shared__ int sh_boff;
    int b = blockIdx.x, tid = threadIdx.x;
    if (tid < 64) {
        int s = (tid < nb) ? bsum[tid] : 0;
        int v = s;
        for (int d = 1; d < 64; d <<= 1) {
            int t = __shfl_up(v, d);
            if (tid >= d) v += t;
        }
        if (tid == b) sh_boff = v - s;                 // exclusive offset of this block
        if (b == 0 && tid == 63) row_ptr[n] = v;       // grand total
    }
    int base = b * 1024 + tid * 4;
    int4e pc[8];                                       // per-plane counts
    int4e v = {0, 0, 0, 0};
#pragma unroll
    for (int c = 0; c < 8; ++c) {
        pc[c] = *reinterpret_cast<const int4e*>(cnt8 + (size_t)c * npl + base);
        v.x += pc[c].x; v.y += pc[c].y; v.z += pc[c].z; v.w += pc[c].w;
    }
    int s = v.x + v.y + v.z + v.w;
    red[tid] = s;
    __syncthreads();
    for (int d = 1; d < 256; d <<= 1) {
        int t = (tid >= d) ? red[tid - d] : 0;
        __syncthreads();
        red[tid] += t;
        __syncthreads();
    }
    int off = sh_boff + red[tid] - s;                  // exclusive prefix for quad
    int4e cur = {off, off + v.x, off + v.x + v.y, off + v.x + v.y + v.z};
    if (base + 0 < n) row_ptr[base + 0] = cur.x;
    if (base + 1 < n) row_ptr[base + 1] = cur.y;
    if (base + 2 < n) row_ptr[base + 2] = cur.z;
    if (base + 3 < n) row_ptr[base + 3] = cur.w;
#pragma unroll
    for (int c = 0; c < 8; ++c) {
        *reinterpret_cast<int4e*>(cnt8 + (size_t)c * npl + base) = cur;
        cur.x += pc[c].x; cur.y += pc[c].y; cur.z += pc[c].z; cur.w += pc[c].w;
    }
}

// CSR fill using privatized cursors (copy = blockIdx&7): /8 atomic contention.
__global__ __launch_bounds__(256) void fill_kernel(const int* __restrict__ ei, int E,
        int* __restrict__ cnt8, int npl,
        const float* __restrict__ dis, int2e* __restrict__ esort) {
    int* mycur = cnt8 + (size_t)(blockIdx.x & 7) * npl;
    int i = blockIdx.x * blockDim.x + threadIdx.x;
    int stride = gridDim.x * blockDim.x;
    int nG = E >> 2;
    for (int g = i; g < nG; g += stride) {
        int4e s4 = *reinterpret_cast<const int4e*>(ei + g * 4);
        int4e d4 = *reinterpret_cast<const int4e*>(ei + E + g * 4);
#pragma unroll
        for (int k = 0; k < 4; ++k) {
            int s = k == 0 ? s4.x : k == 1 ? s4.y : k == 2 ? s4.z : s4.w;
            int d = k == 0 ? d4.x : k == 1 ? d4.y : k == 2 ? d4.z : d4.w;
            int pos = atomicAdd(&mycur[d], 1);
            int2e pkt;
            pkt.x = s;
            pkt.y = __float_as_int(dis[s] * dis[d]);
            esort[pos] = pkt;
        }
    }
    for (int e = nG * 4 + i; e < E; e += stride) {
        int s = ei[e];
        int d = ei[E + e];
        int pos = atomicAdd(&mycur[d], 1);
        int2e pkt;
        pkt.x = s;
        pkt.y = __float_as_int(dis[s] * dis[d]);
        esort[pos] = pkt;
    }
}

// out u16[n][128] = bf16( A[n][128] @ W ),  W given as Wt bf16 [col][k].
// C is written via LDS round-trip -> fully coalesced 16B stores.
__global__ __launch_bounds__(256) void gemm_mfma(const float* __restrict__ A,
        const u16* __restrict__ Wt, u16* __restrict__ out, int n) {
    constexpr int LDA = 136;                 // 128 + 8 pad (bf16) -> 2-way LDS only
    __shared__ u16 as[64 * LDA];
    int tid = threadIdx.x;
    int wave = tid >> 6, lane = tid & 63;
    int row0 = blockIdx.x * 64;
    int l16 = lane & 15;
    int krow = (lane >> 4) * 8;              // k-octet within 32-wide K block

#pragma unroll
    for (int i = 0; i < 8; ++i) {
        int idx = tid + i * 256;             // 2048 quads of 4 f32
        int r = idx >> 5;
        int q = (idx & 31) * 4;
        float4e v = {0.f, 0.f, 0.f, 0.f};
        if (row0 + r < n)
            v = *reinterpret_cast<const float4e*>(A + (size_t)(row0 + r) * 128 + q);
        uint2e p;
        p.x = pack_bf2(v.x, v.y);
        p.y = pack_bf2(v.z, v.w);
        *reinterpret_cast<uint2e*>(&as[r * LDA + q]) = p;
    }

    bf16x8 b[2][4];
#pragma unroll
    for (int n2 = 0; n2 < 2; ++n2)
#pragma unroll
        for (int kb = 0; kb < 4; ++kb)
            b[n2][kb] = *reinterpret_cast<const bf16x8*>(
                Wt + (size_t)(wave * 32 + n2 * 16 + l16) * 128 + kb * 32 + krow);

    __syncthreads();

    f32x4 acc[4][2] = {};
#pragma unroll
    for (int m = 0; m < 4; ++m) {
#pragma unroll
        for (int kb = 0; kb < 4; ++kb) {
            bf16x8 a = *reinterpret_cast<const bf16x8*>(
                &as[(m * 16 + l16) * LDA + kb * 32 + krow]);
#pragma unroll
            for (int n2 = 0; n2 < 2; ++n2)
                acc[m][n2] = __builtin_amdgcn_mfma_f32_16x16x32_bf16(a, b[n2][kb], acc[m][n2], 0, 0, 0);
        }
    }

    __syncthreads();                         // as[] reuse as C-staging
    u16* cs = as;
#pragma unroll
    for (int m = 0; m < 4; ++m) {
        int rb = m * 16 + (lane >> 4) * 4;
#pragma unroll
        for (int n2 = 0; n2 < 2; ++n2) {
            int col = wave * 32 + n2 * 16 + l16;
#pragma unroll
            for (int r = 0; r < 4; ++r)
                cs[(rb + r) * 128 + col] = bf16_1(acc[m][n2][r]);
        }
    }
    __syncthreads();
#pragma unroll
    for (int i = 0; i < 4; ++i) {
        int idx = tid + i * 256;             // 1024 octs: row=idx>>4, oct=(idx&15)
        int r = idx >> 4;
        int q = (idx & 15) * 8;
        if (row0 + r < n)
            *reinterpret_cast<uint4e*>(out + (size_t)(row0 + r) * 128 + q) =
                *reinterpret_cast<const uint4e*>(&cs[r * 128 + q]);
    }
}

// Full-wave gather: lane owns dims 2*lane..2*lane+1, 8 edges in flight.
__device__ __forceinline__ void gather_accum(const uint* __restrict__ xw,
        const int2e* __restrict__ esort, const float* __restrict__ dis,
        int v, int lane, int beg, int end, float& ax, float& ay) {
    int e = beg;
    for (; e + 7 < end; e += 8) {
        int2e ed[8];
        uint vv[8];
#pragma unroll
        for (int j = 0; j < 8; ++j) ed[j] = esort[e + j];
#pragma unroll
        for (int j = 0; j < 8; ++j) vv[j] = xw[(size_t)ed[j].x * 64 + lane];
#pragma unroll
        for (int j = 0; j < 8; ++j) {
            float w = __int_as_float(ed[j].y);
            ax += w * bf_lo(vv[j]);
            ay += w * bf_hi(vv[j]);
        }
    }
    for (; e + 1 < end; e += 2) {
        int2e e0 = esort[e];
        int2e e1 = esort[e + 1];
        uint v0 = xw[(size_t)e0.x * 64 + lane];
        uint v1 = xw[(size_t)e1.x * 64 + lane];
        float w0 = __int_as_float(e0.y), w1 = __int_as_float(e1.y);
        ax += w0 * bf_lo(v0); ay += w0 * bf_hi(v0);
        ax += w1 * bf_lo(v1); ay += w1 * bf_hi(v1);
    }
    if (e < end) {
        int2e e0 = esort[e];
        uint v0 = xw[(size_t)e0.x * 64 + lane];
        float w0 = __int_as_float(e0.y);
        ax += w0 * bf_lo(v0); ay += w0 * bf_hi(v0);
    }
    float dv = dis[v];
    float wv = dv * dv;                            // self-loop norm
    uint vs = xw[(size_t)v * 64 + lane];
    ax += wv * bf_lo(vs); ay += wv * bf_hi(vs);
}

// Pass A: z[v][0..9] = relu(Agg(x@W1)[v] + b1) @ W23   (the one big gather).
__global__ __launch_bounds__(256) void agg_proj_kernel(const uint* __restrict__ xw,
        const int* __restrict__ row_ptr, const int2e* __restrict__ esort,
        const float* __restrict__ dis, const float* __restrict__ b1,
        const float* __restrict__ W23, float* __restrict__ z, int n) {
    int v = (int)((blockIdx.x * blockDim.x + threadIdx.x) >> 6);
    int lane = threadIdx.x & 63;
    if (v >= n) return;
    float ax = 0.f, ay = 0.f;
    gather_accum(xw, esort, dis, v, lane, row_ptr[v], row_ptr[v + 1], ax, ay);
    ax = fmaxf(ax + b1[lane * 2], 0.f);
    ay = fmaxf(ay + b1[lane * 2 + 1], 0.f);
    const float* w0 = W23 + (size_t)lane * 20;     // this lane's 2 rows of W23
    float p[10];
#pragma unroll
    for (int c = 0; c < 10; ++c) p[c] = ax * w0[c] + ay * w0[10 + c];
#pragma unroll
    for (int c = 0; c < 10; ++c) {
#pragma unroll
        for (int d = 1; d < 64; d <<= 1) p[c] += __shfl_xor(p[c], d);
    }
    if (lane < 10) z[(size_t)v * 10 + lane] = p[lane];
}

// Pass B/C: 10-dim aggregation, 4 nodes per wave (16-lane groups, lanes 0-9
// of each group carry dims). FINAL=0: zout = Agg(zin).
// FINAL=1: out = log_softmax(Agg(zin) + s*b23 + b3).
template <int FINAL>
__global__ __launch_bounds__(256) void agg10_kernel(const float* __restrict__ zin,
        const int* __restrict__ row_ptr, const int2e* __restrict__ esort,
        const float* __restrict__ dis, const float* __restrict__ b23,
        const float* __restrict__ b3, float* __restrict__ zout, int n) {
    int wid = (int)((blockIdx.x * blockDim.x + threadIdx.x) >> 6);
    int lane = threadIdx.x & 63;
    int grp = lane >> 4, gl = lane & 15;
    int v = wid * 4 + grp;
    bool act = (v < n);
    bool dl = (gl < 10);
    int beg = act ? row_ptr[v] : 0;
    int end = act ? row_ptr[v + 1] : 0;
    float acc = 0.f, sw = 0.f;
    int e = beg;
    for (; e + 3 < end; e += 4) {
        int2e e0 = esort[e], e1 = esort[e + 1], e2 = esort[e + 2], e3 = esort[e + 3];
        float z0 = dl ? zin[(size_t)e0.x * 10 + gl] : 0.f;
        float z1 = dl ? zin[(size_t)e1.x * 10 + gl] : 0.f;
        float z2 = dl ? zin[(size_t)e2.x * 10 + gl] : 0.f;
        float z3 = dl ? zin[(size_t)e3.x * 10 + gl] : 0.f;
        float w0 = __int_as_float(e0.y), w1 = __int_as_float(e1.y);
        float w2 = __int_as_float(e2.y), w3 = __int_as_float(e3.y);
        acc += w0 * z0 + w1 * z1 + w2 * z2 + w3 * z3;
        sw += (w0 + w1) + (w2 + w3);
    }
    for (; e < end; ++e) {
        int2e e0 = esort[e];
        float z0 = dl ? zin[(size_t)e0.x * 10 + gl] : 0.f;
        float w0 = __int_as_float(e0.y);
        acc += w0 * z0;
        sw += w0;
    }
    if (act) {
        float dv = dis[v];
        float wv = dv * dv;                        // self-loop
        float zs = dl ? zin[(size_t)v * 10 + gl] : 0.f;
        acc += wv * zs;
        sw += wv;
    }
    if (FINAL == 0) {
        if (act && dl) zout[(size_t)v * 10 + gl] = acc;
    } else {
        float p = acc + (dl ? sw * b23[gl] + b3[gl] : 0.f);
        float m = dl ? p : -3.4e38f;
#pragma unroll
        for (int mask = 1; mask < 16; mask <<= 1) m = fmaxf(m, __shfl_xor(m, mask));
        float s = dl ? __expf(p - m) : 0.f;
#pragma unroll
        for (int mask = 1; mask < 16; mask <<= 1) s += __shfl_xor(s, mask);
        float ls = __logf(s);
        if (act && dl) zout[(size_t)v * 10 + gl] = p - m - ls;
    }
}

extern "C" void kernel_launch(void* const* d_in, const int* in_sizes, int n_in,
                              void* d_out, int out_size, void* d_ws, size_t ws_size,
                              hipStream_t stream) {
    const float* x  = (const float*)d_in[0];
    const int*   ei = (const int*)d_in[1];   // [2][E] int32
    const float* W1 = (const float*)d_in[2];
    const float* b1 = (const float*)d_in[3];
    const float* W2 = (const float*)d_in[4];
    const float* b2 = (const float*)d_in[5];
    const float* W3 = (const float*)d_in[6];
    const float* b3 = (const float*)d_in[7];
    int N = in_sizes[0] / 128;
    int E = in_sizes[1] / 2;
    int NB = (N + 1023) / 1024;   // 49 for N=50000 (must be <= 64)
    int NPL = NB * 1024;          // plane stride (padded, zeroed -> unguarded int4)

    char* ws = (char*)d_ws;
    size_t off = 0;
    auto alloc = [&](size_t bytes) -> char* {
        char* p = ws + off;
        off = (off + bytes + 255) & ~(size_t)255;
        return p;
    };
    int*   cnt8    = (int*)alloc((size_t)NPL * 8 * 4);   // 8 privatized planes
    int*   row_ptr = (int*)alloc(((size_t)N + 1) * 4);
    float* dis     = (float*)alloc((size_t)N * 4);
    int*   bsum    = (int*)alloc(64 * 4);
    u16*   Wt1     = (u16*)alloc(128 * 128 * 2);
    float* W23     = (float*)alloc(128 * 10 * 4);
    float* b23     = (float*)alloc(10 * 4);
    int2e* esort   = (int2e*)alloc((size_t)E * 8);
    uint*  bufA    = (uint*)alloc((size_t)N * 64 * 4);   // bf16x2 packed x@W1
    float* z       = (float*)alloc((size_t)N * 10 * 4);  // h1@W23  (2MB, L2-fits)
    float* z2      = (float*)alloc((size_t)N * 10 * 4);  // Agg(z)

    (void)hipMemsetAsync(cnt8, 0, (size_t)NPL * 8 * 4, stream);

    const int NCB = 1024;          // counting blocks

    // --- preprocessing: privatized histogram + weight prep (fused) ---
    count_wt_kernel<<<NCB + 2, 256, 0, stream>>>(ei, E, cnt8, NPL, W1, W2, W3, b2,
                                                 Wt1, W23, b23, NCB);
    // --- layer-1 GEMM (needs Wt1 only) ---
    gemm_mfma<<<(N + 63) / 64, 256, 0, stream>>>(x, Wt1, (u16*)bufA, N);
    scan_partial<<<NB, 256, 0, stream>>>(cnt8, NPL, bsum, dis, N);
    scan_final<<<NB, 256, 0, stream>>>(cnt8, NPL, bsum, row_ptr, NB, N);
    fill_kernel<<<1024, 256, 0, stream>>>(ei, E, cnt8, NPL, dis, esort);
    // --- the single 128-dim gather, fused with ReLU+projection ---
    agg_proj_kernel<<<(N + 3) / 4, 256, 0, stream>>>(bufA, row_ptr, esort, dis, b1, W23, z, N);
    // --- layers 2+3: two 10-dim aggregations (L2-resident table) ---
    agg10_kernel<0><<<(N + 15) / 16, 256, 0, stream>>>(z, row_ptr, esort, dis, nullptr, nullptr, z2, N);
    agg10_kernel<1><<<(N + 15) / 16, 256, 0, stream>>>(z2, row_ptr, esort, dis, b23, b3, (float*)d_out, N);
}

// Round 14
// 186.408 us; speedup vs baseline: 1.0547x; 1.0021x over previous
//
#include <hip/hip_runtime.h>
#include <cstdint>
#include <cstddef>

// ---------------------------------------------------------------------------
// GCN: 3 layers, shared graph.
//   - Algebra: only layer 1 has ReLU; projection commutes with aggregation:
//       out = log_softmax( A^2 (relu(A xW1 + b1) W23) + s*(b2W3) + b3 ).
//     One 128-dim gather (compulsory L2-fill floor: 82MB @ ~1.7TB/s = 48us,
//     invariant R7-R13), then 10-dim f32 space (2MB, L2-resident).
//   - R13 lesson: the 50us "count" cost was a STRAGGLER BLOCK: W23's rolled
//     128-iter serial dependent chain = 640 loads x 200cyc at ILP~1 = 53us
//     while 255 CUs idled (VALU 0.2%, occ 13%). Privatized atomics were a
//     null result -> histogram was never the bottleneck. FIX: one output per
//     thread across 5 blocks, LDS-staged W3, 4 accumulators (ILP 4);
//     b23 via 16-lane groups + shfl reduce.
//   - R11 lesson: don't fuse kernels with opposite resource profiles.
//   - GEMM1: bf16 MFMA 16x16x32, C via LDS round-trip (16B stores).
// ---------------------------------------------------------------------------

typedef unsigned int uint;
typedef unsigned short u16;
typedef uint  uint4e  __attribute__((ext_vector_type(4)));
typedef float float4e __attribute__((ext_vector_type(4)));
typedef uint  uint2e  __attribute__((ext_vector_type(2)));
typedef int   int2e   __attribute__((ext_vector_type(2)));
typedef int   int4e   __attribute__((ext_vector_type(4)));
using bf16x8 = __attribute__((ext_vector_type(8))) short;
using f32x4  = __attribute__((ext_vector_type(4))) float;

__device__ __forceinline__ float bf_lo(uint v) { return __uint_as_float(v << 16); }
__device__ __forceinline__ float bf_hi(uint v) { return __uint_as_float(v & 0xffff0000u); }
__device__ __forceinline__ u16 bf16_1(float a) {
    uint ua = __float_as_uint(a);
    ua = (ua + 0x7fffu + ((ua >> 16) & 1u)) >> 16;          // RNE
    return (u16)ua;
}
__device__ __forceinline__ uint pack_bf2(float a, float b) {
    return (uint)bf16_1(a) | ((uint)bf16_1(b) << 16);
}

// Blocks [0, NCB): privatized degree histogram (copy = blockIdx&7).
// Block NCB: Wt1 transpose + b23 (16-lane groups, shfl reduce).
// Blocks NCB+1..NCB+5: W23 = W2@W3 — ONE output per thread, 4-acc ILP.
__global__ __launch_bounds__(256) void count_wt_kernel(const int* __restrict__ ei, int E,
        int* __restrict__ cnt8, int npl, const float* __restrict__ W1,
        const float* __restrict__ W2, const float* __restrict__ W3,
        const float* __restrict__ b2,
        u16* __restrict__ Wt1, float* __restrict__ W23, float* __restrict__ b23, int ncb) {
    int tid = threadIdx.x;
    int b = blockIdx.x;
    if (b < ncb) {
        int* mycnt = cnt8 + (size_t)(b & 7) * npl;
        int i = b * 256 + tid;
        int stride = ncb * 256;
        int nG = E >> 2;
        for (int g = i; g < nG; g += stride) {
            int4e d = *reinterpret_cast<const int4e*>(ei + E + g * 4);
            atomicAdd(&mycnt[d.x], 1);
            atomicAdd(&mycnt[d.y], 1);
            atomicAdd(&mycnt[d.z], 1);
            atomicAdd(&mycnt[d.w], 1);
        }
        for (int e = nG * 4 + i; e < E; e += stride) atomicAdd(&mycnt[ei[E + e]], 1);
    } else if (b == ncb) {
        for (int i = 0; i < 64; ++i) {
            int idx = tid + i * 256;          // 16384 = 128*128
            int k = idx >> 7, c = idx & 127;
            Wt1[c * 128 + k] = bf16_1(W1[idx]);
        }
        // b23[c] = sum_j b2[j]*W3[j][c]: 16 lanes per output, 8 loads each.
        int c = tid >> 4, j0 = tid & 15;
        float acc = 0.f;
        if (c < 10) {
#pragma unroll
            for (int j = 0; j < 128; j += 16)
                acc += b2[j + j0] * W3[(j + j0) * 10 + c];
        }
#pragma unroll
        for (int m = 1; m < 16; m <<= 1) acc += __shfl_xor(acc, m);
        if (c < 10 && j0 == 0) b23[c] = acc;
    } else {
        // W23: output idx = (b-ncb-1)*256 + tid  (exactly 5*256 = 1280).
        __shared__ float w3s[1280];
        for (int i = tid; i < 1280; i += 256) w3s[i] = W3[i];
        __syncthreads();
        int idx = (b - ncb - 1) * 256 + tid;
        int k = idx / 10, c = idx % 10;
        const float* w2r = W2 + (size_t)k * 128;
        float a0 = 0.f, a1 = 0.f, a2 = 0.f, a3 = 0.f;
#pragma unroll
        for (int j = 0; j < 128; j += 4) {
            a0 += w2r[j + 0] * w3s[(j + 0) * 10 + c];
            a1 += w2r[j + 1] * w3s[(j + 1) * 10 + c];
            a2 += w2r[j + 2] * w3s[(j + 2) * 10 + c];
            a3 += w2r[j + 3] * w3s[(j + 3) * 10 + c];
        }
        W23[idx] = (a0 + a1) + (a2 + a3);
    }
}

// Pass 1: per-block (1024 elems) totals over the 8 planes; dis = rsqrt(deg+1).
__global__ __launch_bounds__(256) void scan_partial(const int* __restrict__ cnt8, int npl,
        int* __restrict__ bsum, float* __restrict__ dis, int n) {
    __shared__ int red[256];
    int b = blockIdx.x, tid = threadIdx.x;
    int base = b * 1024 + tid * 4;
    int4e v = {0, 0, 0, 0};
#pragma unroll
    for (int c = 0; c < 8; ++c) {
        int4e t = *reinterpret_cast<const int4e*>(cnt8 + (size_t)c * npl + base);
        v.x += t.x; v.y += t.y; v.z += t.z; v.w += t.w;
    }
    if (base + 0 < n) dis[base + 0] = rsqrtf((float)(v.x + 1));
    if (base + 1 < n) dis[base + 1] = rsqrtf((float)(v.y + 1));
    if (base + 2 < n) dis[base + 2] = rsqrtf((float)(v.z + 1));
    if (base + 3 < n) dis[base + 3] = rsqrtf((float)(v.w + 1));
    red[tid] = v.x + v.y + v.z + v.w;
    __syncthreads();
    for (int d = 128; d > 0; d >>= 1) {
        if (tid < d) red[tid] += red[tid + d];
        __syncthreads();
    }
    if (tid == 0) bsum[b] = red[0];
}

// Pass 2: block offset via redundant wave scan; block-local exclusive scan ->
// row_ptr; convert cnt8 planes IN PLACE to per-copy cursors.
__global__ __launch_bounds__(256) void scan_final(int* __restrict__ cnt8, int npl,
        const int* __restrict__ bsum, int* __restrict__ row_ptr, int nb, int n) {
    __shared__ int red[256];
    __shared__ int sh_boff;
    int b = blockIdx.x, tid = threadIdx.x;
    if (tid < 64) {
        int s = (tid < nb) ? bsum[tid] : 0;
        int v = s;
        for (int d = 1; d < 64; d <<= 1) {
            int t = __shfl_up(v, d);
            if (tid >= d) v += t;
        }
        if (tid == b) sh_boff = v - s;                 // exclusive offset of this block
        if (b == 0 && tid == 63) row_ptr[n] = v;       // grand total
    }
    int base = b * 1024 + tid * 4;
    int4e pc[8];                                       // per-plane counts
    int4e v = {0, 0, 0, 0};
#pragma unroll
    for (int c = 0; c < 8; ++c) {
        pc[c] = *reinterpret_cast<const int4e*>(cnt8 + (size_t)c * npl + base);
        v.x += pc[c].x; v.y += pc[c].y; v.z += pc[c].z; v.w += pc[c].w;
    }
    int s = v.x + v.y + v.z + v.w;
    red[tid] = s;
    __syncthreads();
    for (int d = 1; d < 256; d <<= 1) {
        int t = (tid >= d) ? red[tid - d] : 0;
        __syncthreads();
        red[tid] += t;
        __syncthreads();
    }
    int off = sh_boff + red[tid] - s;                  // exclusive prefix for quad
    int4e cur = {off, off + v.x, off + v.x + v.y, off + v.x + v.y + v.z};
    if (base + 0 < n) row_ptr[base + 0] = cur.x;
    if (base + 1 < n) row_ptr[base + 1] = cur.y;
    if (base + 2 < n) row_ptr[base + 2] = cur.z;
    if (base + 3 < n) row_ptr[base + 3] = cur.w;
#pragma unroll
    for (int c = 0; c < 8; ++c) {
        *reinterpret_cast<int4e*>(cnt8 + (size_t)c * npl + base) = cur;
        cur.x += pc[c].x; cur.y += pc[c].y; cur.z += pc[c].z; cur.w += pc[c].w;
    }
}

// CSR fill using privatized cursors (copy = blockIdx&7).
__global__ __launch_bounds__(256) void fill_kernel(const int* __restrict__ ei, int E,
        int* __restrict__ cnt8, int npl,
        const float* __restrict__ dis, int2e* __restrict__ esort) {
    int* mycur = cnt8 + (size_t)(blockIdx.x & 7) * npl;
    int i = blockIdx.x * blockDim.x + threadIdx.x;
    int stride = gridDim.x * blockDim.x;
    int nG = E >> 2;
    for (int g = i; g < nG; g += stride) {
        int4e s4 = *reinterpret_cast<const int4e*>(ei + g * 4);
        int4e d4 = *reinterpret_cast<const int4e*>(ei + E + g * 4);
#pragma unroll
        for (int k = 0; k < 4; ++k) {
            int s = k == 0 ? s4.x : k == 1 ? s4.y : k == 2 ? s4.z : s4.w;
            int d = k == 0 ? d4.x : k == 1 ? d4.y : k == 2 ? d4.z : d4.w;
            int pos = atomicAdd(&mycur[d], 1);
            int2e pkt;
            pkt.x = s;
            pkt.y = __float_as_int(dis[s] * dis[d]);
            esort[pos] = pkt;
        }
    }
    for (int e = nG * 4 + i; e < E; e += stride) {
        int s = ei[e];
        int d = ei[E + e];
        int pos = atomicAdd(&mycur[d], 1);
        int2e pkt;
        pkt.x = s;
        pkt.y = __float_as_int(dis[s] * dis[d]);
        esort[pos] = pkt;
    }
}

// out u16[n][128] = bf16( A[n][128] @ W ),  W given as Wt bf16 [col][k].
__global__ __launch_bounds__(256) void gemm_mfma(const float* __restrict__ A,
        const u16* __restrict__ Wt, u16* __restrict__ out, int n) {
    constexpr int LDA = 136;                 // 128 + 8 pad (bf16) -> 2-way LDS only
    __shared__ u16 as[64 * LDA];
    int tid = threadIdx.x;
    int wave = tid >> 6, lane = tid & 63;
    int row0 = blockIdx.x * 64;
    int l16 = lane & 15;
    int krow = (lane >> 4) * 8;              // k-octet within 32-wide K block

#pragma unroll
    for (int i = 0; i < 8; ++i) {
        int idx = tid + i * 256;             // 2048 quads of 4 f32
        int r = idx >> 5;
        int q = (idx & 31) * 4;
        float4e v = {0.f, 0.f, 0.f, 0.f};
        if (row0 + r < n)
            v = *reinterpret_cast<const float4e*>(A + (size_t)(row0 + r) * 128 + q);
        uint2e p;
        p.x = pack_bf2(v.x, v.y);
        p.y = pack_bf2(v.z, v.w);
        *reinterpret_cast<uint2e*>(&as[r * LDA + q]) = p;
    }

    bf16x8 b[2][4];
#pragma unroll
    for (int n2 = 0; n2 < 2; ++n2)
#pragma unroll
        for (int kb = 0; kb < 4; ++kb)
            b[n2][kb] = *reinterpret_cast<const bf16x8*>(
                Wt + (size_t)(wave * 32 + n2 * 16 + l16) * 128 + kb * 32 + krow);

    __syncthreads();

    f32x4 acc[4][2] = {};
#pragma unroll
    for (int m = 0; m < 4; ++m) {
#pragma unroll
        for (int kb = 0; kb < 4; ++kb) {
            bf16x8 a = *reinterpret_cast<const bf16x8*>(
                &as[(m * 16 + l16) * LDA + kb * 32 + krow]);
#pragma unroll
            for (int n2 = 0; n2 < 2; ++n2)
                acc[m][n2] = __builtin_amdgcn_mfma_f32_16x16x32_bf16(a, b[n2][kb], acc[m][n2], 0, 0, 0);
        }
    }

    __syncthreads();                         // as[] reuse as C-staging
    u16* cs = as;
#pragma unroll
    for (int m = 0; m < 4; ++m) {
        int rb = m * 16 + (lane >> 4) * 4;
#pragma unroll
        for (int n2 = 0; n2 < 2; ++n2) {
            int col = wave * 32 + n2 * 16 + l16;
#pragma unroll
            for (int r = 0; r < 4; ++r)
                cs[(rb + r) * 128 + col] = bf16_1(acc[m][n2][r]);
        }
    }
    __syncthreads();
#pragma unroll
    for (int i = 0; i < 4; ++i) {
        int idx = tid + i * 256;             // 1024 octs: row=idx>>4, oct=(idx&15)
        int r = idx >> 4;
        int q = (idx & 15) * 8;
        if (row0 + r < n)
            *reinterpret_cast<uint4e*>(out + (size_t)(row0 + r) * 128 + q) =
                *reinterpret_cast<const uint4e*>(&cs[r * 128 + q]);
    }
}

// Full-wave gather: lane owns dims 2*lane..2*lane+1, 8 edges in flight.
__device__ __forceinline__ void gather_accum(const uint* __restrict__ xw,
        const int2e* __restrict__ esort, const float* __restrict__ dis,
        int v, int lane, int beg, int end, float& ax, float& ay) {
    int e = beg;
    for (; e + 7 < end; e += 8) {
        int2e ed[8];
        uint vv[8];
#pragma unroll
        for (int j = 0; j < 8; ++j) ed[j] = esort[e + j];
#pragma unroll
        for (int j = 0; j < 8; ++j) vv[j] = xw[(size_t)ed[j].x * 64 + lane];
#pragma unroll
        for (int j = 0; j < 8; ++j) {
            float w = __int_as_float(ed[j].y);
            ax += w * bf_lo(vv[j]);
            ay += w * bf_hi(vv[j]);
        }
    }
    for (; e + 1 < end; e += 2) {
        int2e e0 = esort[e];
        int2e e1 = esort[e + 1];
        uint v0 = xw[(size_t)e0.x * 64 + lane];
        uint v1 = xw[(size_t)e1.x * 64 + lane];
        float w0 = __int_as_float(e0.y), w1 = __int_as_float(e1.y);
        ax += w0 * bf_lo(v0); ay += w0 * bf_hi(v0);
        ax += w1 * bf_lo(v1); ay += w1 * bf_hi(v1);
    }
    if (e < end) {
        int2e e0 = esort[e];
        uint v0 = xw[(size_t)e0.x * 64 + lane];
        float w0 = __int_as_float(e0.y);
        ax += w0 * bf_lo(v0); ay += w0 * bf_hi(v0);
    }
    float dv = dis[v];
    float wv = dv * dv;                            // self-loop norm
    uint vs = xw[(size_t)v * 64 + lane];
    ax += wv * bf_lo(vs); ay += wv * bf_hi(vs);
}

// Pass A: z[v][0..9] = relu(Agg(x@W1)[v] + b1) @ W23   (the one big gather).
__global__ __launch_bounds__(256) void agg_proj_kernel(const uint* __restrict__ xw,
        const int* __restrict__ row_ptr, const int2e* __restrict__ esort,
        const float* __restrict__ dis, const float* __restrict__ b1,
        const float* __restrict__ W23, float* __restrict__ z, int n) {
    int v = (int)((blockIdx.x * blockDim.x + threadIdx.x) >> 6);
    int lane = threadIdx.x & 63;
    if (v >= n) return;
    float ax = 0.f, ay = 0.f;
    gather_accum(xw, esort, dis, v, lane, row_ptr[v], row_ptr[v + 1], ax, ay);
    ax = fmaxf(ax + b1[lane * 2], 0.f);
    ay = fmaxf(ay + b1[lane * 2 + 1], 0.f);
    const float* w0 = W23 + (size_t)lane * 20;     // this lane's 2 rows of W23
    float p[10];
#pragma unroll
    for (int c = 0; c < 10; ++c) p[c] = ax * w0[c] + ay * w0[10 + c];
#pragma unroll
    for (int c = 0; c < 10; ++c) {
#pragma unroll
        for (int d = 1; d < 64; d <<= 1) p[c] += __shfl_xor(p[c], d);
    }
    if (lane < 10) z[(size_t)v * 10 + lane] = p[lane];
}

// Pass B/C: 10-dim aggregation, 4 nodes per wave (16-lane groups).
// FINAL=0: zout = Agg(zin).  FINAL=1: log_softmax(Agg(zin) + s*b23 + b3).
template <int FINAL>
__global__ __launch_bounds__(256) void agg10_kernel(const float* __restrict__ zin,
        const int* __restrict__ row_ptr, const int2e* __restrict__ esort,
        const float* __restrict__ dis, const float* __restrict__ b23,
        const float* __restrict__ b3, float* __restrict__ zout, int n) {
    int wid = (int)((blockIdx.x * blockDim.x + threadIdx.x) >> 6);
    int lane = threadIdx.x & 63;
    int grp = lane >> 4, gl = lane & 15;
    int v = wid * 4 + grp;
    bool act = (v < n);
    bool dl = (gl < 10);
    int beg = act ? row_ptr[v] : 0;
    int end = act ? row_ptr[v + 1] : 0;
    float acc = 0.f, sw = 0.f;
    int e = beg;
    for (; e + 3 < end; e += 4) {
        int2e e0 = esort[e], e1 = esort[e + 1], e2 = esort[e + 2], e3 = esort[e + 3];
        float z0 = dl ? zin[(size_t)e0.x * 10 + gl] : 0.f;
        float z1 = dl ? zin[(size_t)e1.x * 10 + gl] : 0.f;
        float z2 = dl ? zin[(size_t)e2.x * 10 + gl] : 0.f;
        float z3 = dl ? zin[(size_t)e3.x * 10 + gl] : 0.f;
        float w0 = __int_as_float(e0.y), w1 = __int_as_float(e1.y);
        float w2 = __int_as_float(e2.y), w3 = __int_as_float(e3.y);
        acc += w0 * z0 + w1 * z1 + w2 * z2 + w3 * z3;
        sw += (w0 + w1) + (w2 + w3);
    }
    for (; e < end; ++e) {
        int2e e0 = esort[e];
        float z0 = dl ? zin[(size_t)e0.x * 10 + gl] : 0.f;
        float w0 = __int_as_float(e0.y);
        acc += w0 * z0;
        sw += w0;
    }
    if (act) {
        float dv = dis[v];
        float wv = dv * dv;                        // self-loop
        float zs = dl ? zin[(size_t)v * 10 + gl] : 0.f;
        acc += wv * zs;
        sw += wv;
    }
    if (FINAL == 0) {
        if (act && dl) zout[(size_t)v * 10 + gl] = acc;
    } else {
        float p = acc + (dl ? sw * b23[gl] + b3[gl] : 0.f);
        float m = dl ? p : -3.4e38f;
#pragma unroll
        for (int mask = 1; mask < 16; mask <<= 1) m = fmaxf(m, __shfl_xor(m, mask));
        float s = dl ? __expf(p - m) : 0.f;
#pragma unroll
        for (int mask = 1; mask < 16; mask <<= 1) s += __shfl_xor(s, mask);
        float ls = __logf(s);
        if (act && dl) zout[(size_t)v * 10 + gl] = p - m - ls;
    }
}

extern "C" void kernel_launch(void* const* d_in, const int* in_sizes, int n_in,
                              void* d_out, int out_size, void* d_ws, size_t ws_size,
                              hipStream_t stream) {
    const float* x  = (const float*)d_in[0];
    const int*   ei = (const int*)d_in[1];   // [2][E] int32
    const float* W1 = (const float*)d_in[2];
    const float* b1 = (const float*)d_in[3];
    const float* W2 = (const float*)d_in[4];
    const float* b2 = (const float*)d_in[5];
    const float* W3 = (const float*)d_in[6];
    const float* b3 = (const float*)d_in[7];
    int N = in_sizes[0] / 128;
    int E = in_sizes[1] / 2;
    int NB = (N + 1023) / 1024;   // 49 for N=50000 (must be <= 64)
    int NPL = NB * 1024;          // plane stride (padded, zeroed -> unguarded int4)

    char* ws = (char*)d_ws;
    size_t off = 0;
    auto alloc = [&](size_t bytes) -> char* {
        char* p = ws + off;
        off = (off + bytes + 255) & ~(size_t)255;
        return p;
    };
    int*   cnt8    = (int*)alloc((size_t)NPL * 8 * 4);   // 8 privatized planes
    int*   row_ptr = (int*)alloc(((size_t)N + 1) * 4);
    float* dis     = (float*)alloc((size_t)N * 4);
    int*   bsum    = (int*)alloc(64 * 4);
    u16*   Wt1     = (u16*)alloc(128 * 128 * 2);
    float* W23     = (float*)alloc(128 * 10 * 4);
    float* b23     = (float*)alloc(10 * 4);
    int2e* esort   = (int2e*)alloc((size_t)E * 8);
    uint*  bufA    = (uint*)alloc((size_t)N * 64 * 4);   // bf16x2 packed x@W1
    float* z       = (float*)alloc((size_t)N * 10 * 4);  // h1@W23  (2MB, L2-fits)
    float* z2      = (float*)alloc((size_t)N * 10 * 4);  // Agg(z)

    (void)hipMemsetAsync(cnt8, 0, (size_t)NPL * 8 * 4, stream);

    const int NCB = 1024;          // counting blocks

    // --- preprocessing: histogram + weight prep (parallelized W23/b23) ---
    count_wt_kernel<<<NCB + 6, 256, 0, stream>>>(ei, E, cnt8, NPL, W1, W2, W3, b2,
                                                 Wt1, W23, b23, NCB);
    // --- layer-1 GEMM (needs Wt1 only) ---
    gemm_mfma<<<(N + 63) / 64, 256, 0, stream>>>(x, Wt1, (u16*)bufA, N);
    scan_partial<<<NB, 256, 0, stream>>>(cnt8, NPL, bsum, dis, N);
    scan_final<<<NB, 256, 0, stream>>>(cnt8, NPL, bsum, row_ptr, NB, N);
    fill_kernel<<<1024, 256, 0, stream>>>(ei, E, cnt8, NPL, dis, esort);
    // --- the single 128-dim gather, fused with ReLU+projection ---
    agg_proj_kernel<<<(N + 3) / 4, 256, 0, stream>>>(bufA, row_ptr, esort, dis, b1, W23, z, N);
    // --- layers 2+3: two 10-dim aggregations (L2-resident table) ---
    agg10_kernel<0><<<(N + 15) / 16, 256, 0, stream>>>(z, row_ptr, esort, dis, nullptr, nullptr, z2, N);
    agg10_kernel<1><<<(N + 15) / 16, 256, 0, stream>>>(z2, row_ptr, esort, dis, b23, b3, (float*)d_out, N);
}

// Round 15
// 140.585 us; speedup vs baseline: 1.3984x; 1.3259x over previous
//
#include <hip/hip_runtime.h>
#include <cstdint>
#include <cstddef>

// ---------------------------------------------------------------------------
// GCN: 3 layers, shared graph.
//   - Algebra: only layer 1 has ReLU; projection commutes with aggregation:
//       out = log_softmax( A^2 (relu(A xW1 + b1) W23) + s*(b2W3) + b3 ).
//     One 128-dim gather (compulsory L2-fill floor: 82MB @ ~1.7TB/s = 48us,
//     invariant R7-R14), then 10-dim f32 space (2MB, L2-resident).
//   - R14 lesson: device-scope global atomics WRITE THROUGH to the memory
//     side (~32B/op: count_wt WRITE_SIZE 24.9MB = 800k x 32B) and cap at
//     ~16G atomics/s regardless of privatization (R13 null). count+fill were
//     ~85us of atomic tax. FIX: two-level counting sort, ALL atomics in LDS:
//       passA: 256 blocks x LDS coarse histogram (196 buckets of 256 nodes)
//       scan1/scan2: (bucket x block) cursor scan + bucket bases
//       passB: scatter edges -> bucket-contiguous ebkt via LDS cursors
//       passC: block per bucket: LDS fine count+scan -> deg/dis/row_ptr,
//              scatter to dst-sorted esort (src,dst)
//       normfix: (src,dst) -> (src, dis[src]*dis[dst])  [dis L2-resident]
//     Downstream gather kernels see the same esort/row_ptr as before.
//   - R11 lesson: don't fuse kernels with opposite resource profiles.
//   - GEMM1: bf16 MFMA 16x16x32, C via LDS round-trip (16B stores).
// ---------------------------------------------------------------------------

typedef unsigned int uint;
typedef unsigned short u16;
typedef uint  uint4e  __attribute__((ext_vector_type(4)));
typedef float float4e __attribute__((ext_vector_type(4)));
typedef uint  uint2e  __attribute__((ext_vector_type(2)));
typedef int   int2e   __attribute__((ext_vector_type(2)));
typedef int   int4e   __attribute__((ext_vector_type(4)));
using bf16x8 = __attribute__((ext_vector_type(8))) short;
using f32x4  = __attribute__((ext_vector_type(4))) float;

__device__ __forceinline__ float bf_lo(uint v) { return __uint_as_float(v << 16); }
__device__ __forceinline__ float bf_hi(uint v) { return __uint_as_float(v & 0xffff0000u); }
__device__ __forceinline__ u16 bf16_1(float a) {
    uint ua = __float_as_uint(a);
    ua = (ua + 0x7fffu + ((ua >> 16) & 1u)) >> 16;          // RNE
    return (u16)ua;
}
__device__ __forceinline__ uint pack_bf2(float a, float b) {
    return (uint)bf16_1(a) | ((uint)bf16_1(b) << 16);
}

// Blocks [0,nca): coarse histogram of dst buckets (dst>>8) in LDS ->
// cntA[bucket*nca + block]. Block nca: Wt1 transpose + b23. Blocks nca+1..+5: W23.
__global__ __launch_bounds__(256) void passA_wt(const int* __restrict__ ei, int E,
        int* __restrict__ cntA, int nbkt, int nca,
        const float* __restrict__ W1, const float* __restrict__ W2,
        const float* __restrict__ W3, const float* __restrict__ b2,
        u16* __restrict__ Wt1, float* __restrict__ W23, float* __restrict__ b23) {
    int tid = threadIdx.x, b = blockIdx.x;
    if (b < nca) {
        __shared__ int h[256];
        h[tid] = 0;
        __syncthreads();
        int ch = (E + nca - 1) / nca;
        int beg = b * ch, end = min(beg + ch, E);
        for (int e = beg + tid; e < end; e += 256)
            atomicAdd(&h[ei[E + e] >> 8], 1);               // LDS atomic
        __syncthreads();
        if (tid < nbkt) cntA[tid * nca + b] = h[tid];       // all entries written
    } else if (b == nca) {
        for (int i = 0; i < 64; ++i) {
            int idx = tid + i * 256;          // 16384 = 128*128
            int k = idx >> 7, c = idx & 127;
            Wt1[c * 128 + k] = bf16_1(W1[idx]);
        }
        // b23[c] = sum_j b2[j]*W3[j][c]: 16 lanes per output.
        int c = tid >> 4, j0 = tid & 15;
        float acc = 0.f;
        if (c < 10) {
#pragma unroll
            for (int j = 0; j < 128; j += 16)
                acc += b2[j + j0] * W3[(j + j0) * 10 + c];
        }
#pragma unroll
        for (int m = 1; m < 16; m <<= 1) acc += __shfl_xor(acc, m);
        if (c < 10 && j0 == 0) b23[c] = acc;
    } else {
        // W23: one output per thread, idx = (b-nca-1)*256 + tid (5*256=1280).
        __shared__ float w3s[1280];
        for (int i = tid; i < 1280; i += 256) w3s[i] = W3[i];
        __syncthreads();
        int idx = (b - nca - 1) * 256 + tid;
        int k = idx / 10, c = idx % 10;
        const float* w2r = W2 + (size_t)k * 128;
        float a0 = 0.f, a1 = 0.f, a2 = 0.f, a3 = 0.f;
#pragma unroll
        for (int j = 0; j < 128; j += 4) {
            a0 += w2r[j + 0] * w3s[(j + 0) * 10 + c];
            a1 += w2r[j + 1] * w3s[(j + 1) * 10 + c];
            a2 += w2r[j + 2] * w3s[(j + 2) * 10 + c];
            a3 += w2r[j + 3] * w3s[(j + 3) * 10 + c];
        }
        W23[idx] = (a0 + a1) + (a2 + a3);
    }
}

// Per-bucket exclusive scan over the nca block counts; total -> btot[bucket].
__global__ __launch_bounds__(256) void scan1(int* __restrict__ cntA, int nca,
        int* __restrict__ btot) {
    __shared__ int s[256];
    int b = blockIdx.x, tid = threadIdx.x;   // b = bucket; tid = chunk-block
    int v = cntA[b * nca + tid];
    s[tid] = v;
    __syncthreads();
    for (int d = 1; d < 256; d <<= 1) {
        int t = (tid >= d) ? s[tid - d] : 0;
        __syncthreads();
        s[tid] += t;
        __syncthreads();
    }
    cntA[b * nca + tid] = s[tid] - v;        // exclusive within bucket
    if (tid == 255) btot[b] = s[255];
}

// Exclusive scan of bucket totals -> bktbase; set sentinels.
__global__ __launch_bounds__(256) void scan2(const int* __restrict__ btot, int nbkt,
        int* __restrict__ bktbase, int* __restrict__ row_ptr, int n, int E) {
    __shared__ int s[256];
    int tid = threadIdx.x;
    int v = (tid < nbkt) ? btot[tid] : 0;
    s[tid] = v;
    __syncthreads();
    for (int d = 1; d < 256; d <<= 1) {
        int t = (tid >= d) ? s[tid - d] : 0;
        __syncthreads();
        s[tid] += t;
        __syncthreads();
    }
    if (tid < nbkt) bktbase[tid] = s[tid] - v;
    if (tid == 0) { bktbase[nbkt] = E; row_ptr[n] = E; }
}

// Scatter edges into bucket-contiguous ebkt via LDS cursors (no global atomics).
__global__ __launch_bounds__(256) void passB(const int* __restrict__ ei, int E,
        const int* __restrict__ cntA, int nca, int nbkt,
        const int* __restrict__ bktbase, int2e* __restrict__ ebkt) {
    __shared__ int cur[256];
    int tid = threadIdx.x, b = blockIdx.x;
    if (tid < nbkt) cur[tid] = bktbase[tid] + cntA[tid * nca + b];
    __syncthreads();
    int ch = (E + nca - 1) / nca;
    int beg = b * ch, end = min(beg + ch, E);
    for (int e = beg + tid; e < end; e += 256) {
        int s = ei[e], d = ei[E + e];
        int pos = atomicAdd(&cur[d >> 8], 1);               // LDS atomic
        int2e pkt;
        pkt.x = s;
        pkt.y = d;
        ebkt[pos] = pkt;
    }
}

// Per-bucket fine counting sort: deg/dis/row_ptr + dst-sorted esort (src,dst).
__global__ __launch_bounds__(256) void passC(const int2e* __restrict__ ebkt,
        const int* __restrict__ bktbase, int2e* __restrict__ esort,
        int* __restrict__ row_ptr, float* __restrict__ dis, int n) {
    __shared__ int fc[256];
    __shared__ int sc[256];
    int k = blockIdx.x, tid = threadIdx.x;
    int base = bktbase[k], endb = bktbase[k + 1];
    int node0 = k << 8;
    fc[tid] = 0;
    __syncthreads();
    for (int i = base + tid; i < endb; i += 256)
        atomicAdd(&fc[ebkt[i].y & 255], 1);                 // LDS atomic
    __syncthreads();
    int v = fc[tid];
    sc[tid] = v;
    __syncthreads();
    for (int d = 1; d < 256; d <<= 1) {
        int t = (tid >= d) ? sc[tid - d] : 0;
        __syncthreads();
        sc[tid] += t;
        __syncthreads();
    }
    int excl = sc[tid] - v;
    if (node0 + tid < n) {
        dis[node0 + tid] = rsqrtf((float)(v + 1));          // +1 self-loop
        row_ptr[node0 + tid] = base + excl;
    }
    __syncthreads();
    fc[tid] = base + excl;                                  // reuse as cursor
    __syncthreads();
    for (int i = base + tid; i < endb; i += 256) {
        int2e ed = ebkt[i];
        int pos = atomicAdd(&fc[ed.y & 255], 1);            // LDS atomic
        esort[pos] = ed;                                    // still (src,dst)
    }
}

// Rewrite esort: (src,dst) -> (src, dis[src]*dis[dst]). dis is L2-resident.
__global__ __launch_bounds__(256) void normfix(int2e* __restrict__ esort,
        const float* __restrict__ dis, int E) {
    int i = blockIdx.x * blockDim.x + threadIdx.x;
    int stride = gridDim.x * blockDim.x;
    for (int e = i; e < E; e += stride) {
        int2e ed = esort[e];
        float w = dis[ed.x] * dis[ed.y];
        ed.y = __float_as_int(w);
        esort[e] = ed;
    }
}

// out u16[n][128] = bf16( A[n][128] @ W ),  W given as Wt bf16 [col][k].
__global__ __launch_bounds__(256) void gemm_mfma(const float* __restrict__ A,
        const u16* __restrict__ Wt, u16* __restrict__ out, int n) {
    constexpr int LDA = 136;                 // 128 + 8 pad (bf16) -> 2-way LDS only
    __shared__ u16 as[64 * LDA];
    int tid = threadIdx.x;
    int wave = tid >> 6, lane = tid & 63;
    int row0 = blockIdx.x * 64;
    int l16 = lane & 15;
    int krow = (lane >> 4) * 8;              // k-octet within 32-wide K block

#pragma unroll
    for (int i = 0; i < 8; ++i) {
        int idx = tid + i * 256;             // 2048 quads of 4 f32
        int r = idx >> 5;
        int q = (idx & 31) * 4;
        float4e v = {0.f, 0.f, 0.f, 0.f};
        if (row0 + r < n)
            v = *reinterpret_cast<const float4e*>(A + (size_t)(row0 + r) * 128 + q);
        uint2e p;
        p.x = pack_bf2(v.x, v.y);
        p.y = pack_bf2(v.z, v.w);
        *reinterpret_cast<uint2e*>(&as[r * LDA + q]) = p;
    }

    bf16x8 b[2][4];
#pragma unroll
    for (int n2 = 0; n2 < 2; ++n2)
#pragma unroll
        for (int kb = 0; kb < 4; ++kb)
            b[n2][kb] = *reinterpret_cast<const bf16x8*>(
                Wt + (size_t)(wave * 32 + n2 * 16 + l16) * 128 + kb * 32 + krow);

    __syncthreads();

    f32x4 acc[4][2] = {};
#pragma unroll
    for (int m = 0; m < 4; ++m) {
#pragma unroll
        for (int kb = 0; kb < 4; ++kb) {
            bf16x8 a = *reinterpret_cast<const bf16x8*>(
                &as[(m * 16 + l16) * LDA + kb * 32 + krow]);
#pragma unroll
            for (int n2 = 0; n2 < 2; ++n2)
                acc[m][n2] = __builtin_amdgcn_mfma_f32_16x16x32_bf16(a, b[n2][kb], acc[m][n2], 0, 0, 0);
        }
    }

    __syncthreads();                         // as[] reuse as C-staging
    u16* cs = as;
#pragma unroll
    for (int m = 0; m < 4; ++m) {
        int rb = m * 16 + (lane >> 4) * 4;
#pragma unroll
        for (int n2 = 0; n2 < 2; ++n2) {
            int col = wave * 32 + n2 * 16 + l16;
#pragma unroll
            for (int r = 0; r < 4; ++r)
                cs[(rb + r) * 128 + col] = bf16_1(acc[m][n2][r]);
        }
    }
    __syncthreads();
#pragma unroll
    for (int i = 0; i < 4; ++i) {
        int idx = tid + i * 256;             // 1024 octs: row=idx>>4, oct=(idx&15)
        int r = idx >> 4;
        int q = (idx & 15) * 8;
        if (row0 + r < n)
            *reinterpret_cast<uint4e*>(out + (size_t)(row0 + r) * 128 + q) =
                *reinterpret_cast<const uint4e*>(&cs[r * 128 + q]);
    }
}

// Full-wave gather: lane owns dims 2*lane..2*lane+1, 8 edges in flight.
__device__ __forceinline__ void gather_accum(const uint* __restrict__ xw,
        const int2e* __restrict__ esort, const float* __restrict__ dis,
        int v, int lane, int beg, int end, float& ax, float& ay) {
    int e = beg;
    for (; e + 7 < end; e += 8) {
        int2e ed[8];
        uint vv[8];
#pragma unroll
        for (int j = 0; j < 8; ++j) ed[j] = esort[e + j];
#pragma unroll
        for (int j = 0; j < 8; ++j) vv[j] = xw[(size_t)ed[j].x * 64 + lane];
#pragma unroll
        for (int j = 0; j < 8; ++j) {
            float w = __int_as_float(ed[j].y);
            ax += w * bf_lo(vv[j]);
            ay += w * bf_hi(vv[j]);
        }
    }
    for (; e + 1 < end; e += 2) {
        int2e e0 = esort[e];
        int2e e1 = esort[e + 1];
        uint v0 = xw[(size_t)e0.x * 64 + lane];
        uint v1 = xw[(size_t)e1.x * 64 + lane];
        float w0 = __int_as_float(e0.y), w1 = __int_as_float(e1.y);
        ax += w0 * bf_lo(v0); ay += w0 * bf_hi(v0);
        ax += w1 * bf_lo(v1); ay += w1 * bf_hi(v1);
    }
    if (e < end) {
        int2e e0 = esort[e];
        uint v0 = xw[(size_t)e0.x * 64 + lane];
        float w0 = __int_as_float(e0.y);
        ax += w0 * bf_lo(v0); ay += w0 * bf_hi(v0);
    }
    float dv = dis[v];
    float wv = dv * dv;                            // self-loop norm
    uint vs = xw[(size_t)v * 64 + lane];
    ax += wv * bf_lo(vs); ay += wv * bf_hi(vs);
}

// Pass A: z[v][0..9] = relu(Agg(x@W1)[v] + b1) @ W23   (the one big gather).
__global__ __launch_bounds__(256) void agg_proj_kernel(const uint* __restrict__ xw,
        const int* __restrict__ row_ptr, const int2e* __restrict__ esort,
        const float* __restrict__ dis, const float* __restrict__ b1,
        const float* __restrict__ W23, float* __restrict__ z, int n) {
    int v = (int)((blockIdx.x * blockDim.x + threadIdx.x) >> 6);
    int lane = threadIdx.x & 63;
    if (v >= n) return;
    float ax = 0.f, ay = 0.f;
    gather_accum(xw, esort, dis, v, lane, row_ptr[v], row_ptr[v + 1], ax, ay);
    ax = fmaxf(ax + b1[lane * 2], 0.f);
    ay = fmaxf(ay + b1[lane * 2 + 1], 0.f);
    const float* w0 = W23 + (size_t)lane * 20;     // this lane's 2 rows of W23
    float p[10];
#pragma unroll
    for (int c = 0; c < 10; ++c) p[c] = ax * w0[c] + ay * w0[10 + c];
#pragma unroll
    for (int c = 0; c < 10; ++c) {
#pragma unroll
        for (int d = 1; d < 64; d <<= 1) p[c] += __shfl_xor(p[c], d);
    }
    if (lane < 10) z[(size_t)v * 10 + lane] = p[lane];
}

// Pass B/C: 10-dim aggregation, 4 nodes per wave (16-lane groups).
// FINAL=0: zout = Agg(zin).  FINAL=1: log_softmax(Agg(zin) + s*b23 + b3).
template <int FINAL>
__global__ __launch_bounds__(256) void agg10_kernel(const float* __restrict__ zin,
        const int* __restrict__ row_ptr, const int2e* __restrict__ esort,
        const float* __restrict__ dis, const float* __restrict__ b23,
        const float* __restrict__ b3, float* __restrict__ zout, int n) {
    int wid = (int)((blockIdx.x * blockDim.x + threadIdx.x) >> 6);
    int lane = threadIdx.x & 63;
    int grp = lane >> 4, gl = lane & 15;
    int v = wid * 4 + grp;
    bool act = (v < n);
    bool dl = (gl < 10);
    int beg = act ? row_ptr[v] : 0;
    int end = act ? row_ptr[v + 1] : 0;
    float acc = 0.f, sw = 0.f;
    int e = beg;
    for (; e + 3 < end; e += 4) {
        int2e e0 = esort[e], e1 = esort[e + 1], e2 = esort[e + 2], e3 = esort[e + 3];
        float z0 = dl ? zin[(size_t)e0.x * 10 + gl] : 0.f;
        float z1 = dl ? zin[(size_t)e1.x * 10 + gl] : 0.f;
        float z2 = dl ? zin[(size_t)e2.x * 10 + gl] : 0.f;
        float z3 = dl ? zin[(size_t)e3.x * 10 + gl] : 0.f;
        float w0 = __int_as_float(e0.y), w1 = __int_as_float(e1.y);
        float w2 = __int_as_float(e2.y), w3 = __int_as_float(e3.y);
        acc += w0 * z0 + w1 * z1 + w2 * z2 + w3 * z3;
        sw += (w0 + w1) + (w2 + w3);
    }
    for (; e < end; ++e) {
        int2e e0 = esort[e];
        float z0 = dl ? zin[(size_t)e0.x * 10 + gl] : 0.f;
        float w0 = __int_as_float(e0.y);
        acc += w0 * z0;
        sw += w0;
    }
    if (act) {
        float dv = dis[v];
        float wv = dv * dv;                        // self-loop
        float zs = dl ? zin[(size_t)v * 10 + gl] : 0.f;
        acc += wv * zs;
        sw += wv;
    }
    if (FINAL == 0) {
        if (act && dl) zout[(size_t)v * 10 + gl] = acc;
    } else {
        float p = acc + (dl ? sw * b23[gl] + b3[gl] : 0.f);
        float m = dl ? p : -3.4e38f;
#pragma unroll
        for (int mask = 1; mask < 16; mask <<= 1) m = fmaxf(m, __shfl_xor(m, mask));
        float s = dl ? __expf(p - m) : 0.f;
#pragma unroll
        for (int mask = 1; mask < 16; mask <<= 1) s += __shfl_xor(s, mask);
        float ls = __logf(s);
        if (act && dl) zout[(size_t)v * 10 + gl] = p - m - ls;
    }
}

extern "C" void kernel_launch(void* const* d_in, const int* in_sizes, int n_in,
                              void* d_out, int out_size, void* d_ws, size_t ws_size,
                              hipStream_t stream) {
    const float* x  = (const float*)d_in[0];
    const int*   ei = (const int*)d_in[1];   // [2][E] int32
    const float* W1 = (const float*)d_in[2];
    const float* b1 = (const float*)d_in[3];
    const float* W2 = (const float*)d_in[4];
    const float* b2 = (const float*)d_in[5];
    const float* W3 = (const float*)d_in[6];
    const float* b3 = (const float*)d_in[7];
    int N = in_sizes[0] / 128;
    int E = in_sizes[1] / 2;
    int NBKT = (N + 255) >> 8;    // 196 for N=50000 (must be <= 256)
    const int NCA = 256;          // chunk blocks for passes A/B

    char* ws = (char*)d_ws;
    size_t off = 0;
    auto alloc = [&](size_t bytes) -> char* {
        char* p = ws + off;
        off = (off + bytes + 255) & ~(size_t)255;
        return p;
    };
    int*   cntA    = (int*)alloc((size_t)NBKT * NCA * 4);  // (bucket x block) counts
    int*   btot    = (int*)alloc(256 * 4);
    int*   bktbase = (int*)alloc(257 * 4);
    int*   row_ptr = (int*)alloc(((size_t)N + 1) * 4);
    float* dis     = (float*)alloc((size_t)N * 4);
    u16*   Wt1     = (u16*)alloc(128 * 128 * 2);
    float* W23     = (float*)alloc(128 * 10 * 4);
    float* b23     = (float*)alloc(10 * 4);
    int2e* ebkt    = (int2e*)alloc((size_t)E * 8);         // bucket-sorted (src,dst)
    int2e* esort   = (int2e*)alloc((size_t)E * 8);         // dst-sorted (src,w)
    uint*  bufA    = (uint*)alloc((size_t)N * 64 * 4);     // bf16x2 packed x@W1
    float* z       = (float*)alloc((size_t)N * 10 * 4);    // h1@W23 (2MB, L2-fits)
    float* z2      = (float*)alloc((size_t)N * 10 * 4);    // Agg(z)

    // --- preprocessing: LDS-atomic counting sort + weight prep (no memset) ---
    passA_wt<<<NCA + 6, 256, 0, stream>>>(ei, E, cntA, NBKT, NCA, W1, W2, W3, b2,
                                          Wt1, W23, b23);
    // layer-1 GEMM (needs Wt1 only; runs while sort machinery proceeds)
    gemm_mfma<<<(N + 63) / 64, 256, 0, stream>>>(x, Wt1, (u16*)bufA, N);
    scan1<<<NBKT, 256, 0, stream>>>(cntA, NCA, btot);
    scan2<<<1, 256, 0, stream>>>(btot, NBKT, bktbase, row_ptr, N, E);
    passB<<<NCA, 256, 0, stream>>>(ei, E, cntA, NCA, NBKT, bktbase, ebkt);
    passC<<<NBKT, 256, 0, stream>>>(ebkt, bktbase, esort, row_ptr, dis, N);
    normfix<<<1024, 256, 0, stream>>>(esort, dis, E);
    // --- the single 128-dim gather, fused with ReLU+projection ---
    agg_proj_kernel<<<(N + 3) / 4, 256, 0, stream>>>(bufA, row_ptr, esort, dis, b1, W23, z, N);
    // --- layers 2+3: two 10-dim aggregations (L2-resident table) ---
    agg10_kernel<0><<<(N + 15) / 16, 256, 0, stream>>>(z, row_ptr, esort, dis, nullptr, nullptr, z2, N);
    agg10_kernel<1><<<(N + 15) / 16, 256, 0, stream>>>(z2, row_ptr, esort, dis, b23, b3, (float*)d_out, N);
}

// Round 16
// 135.316 us; speedup vs baseline: 1.4529x; 1.0389x over previous
//
#include <hip/hip_runtime.h>
#include <cstdint>
#include <cstddef>

// ---------------------------------------------------------------------------
// GCN: 3 layers, shared graph.
//   - Algebra: only layer 1 has ReLU; projection commutes with aggregation:
//       out = log_softmax( A^2 (relu(A xW1 + b1) W23) + s*(b2W3) + b3 ).
//     One 128-dim gather (compulsory L2-fill floor: 82MB @ ~1.7TB/s = 48us,
//     invariant R7-R15), then 10-dim f32 space (2MB, L2-resident).
//   - R14/R15 lesson: device-scope global atomics write through (~32B/op);
//     LDS-atomic two-level counting sort removed ~46us of atomic tax.
//   - R16: esort stays (src,dst); gathers compute w = dis[s]*dis[d] on the
//     fly (dis 200KB L2-hot; gathers are fill-bound, not issue-bound), which
//     deletes the normfix round-trip. passB/passC derive bucket bases by a
//     redundant 196-entry LDS scan of btot, deleting scan2. 8 launches.
//   - R11 lesson: don't fuse kernels with opposite resource profiles.
//   - GEMM1: bf16 MFMA 16x16x32, C via LDS round-trip (16B stores).
// ---------------------------------------------------------------------------

typedef unsigned int uint;
typedef unsigned short u16;
typedef uint  uint4e  __attribute__((ext_vector_type(4)));
typedef float float4e __attribute__((ext_vector_type(4)));
typedef uint  uint2e  __attribute__((ext_vector_type(2)));
typedef int   int2e   __attribute__((ext_vector_type(2)));
typedef int   int4e   __attribute__((ext_vector_type(4)));
using bf16x8 = __attribute__((ext_vector_type(8))) short;
using f32x4  = __attribute__((ext_vector_type(4))) float;

__device__ __forceinline__ float bf_lo(uint v) { return __uint_as_float(v << 16); }
__device__ __forceinline__ float bf_hi(uint v) { return __uint_as_float(v & 0xffff0000u); }
__device__ __forceinline__ u16 bf16_1(float a) {
    uint ua = __float_as_uint(a);
    ua = (ua + 0x7fffu + ((ua >> 16) & 1u)) >> 16;          // RNE
    return (u16)ua;
}
__device__ __forceinline__ uint pack_bf2(float a, float b) {
    return (uint)bf16_1(a) | ((uint)bf16_1(b) << 16);
}

// Blocks [0,nca): coarse histogram of dst buckets (dst>>8) in LDS ->
// cntA[bucket*nca + block]. Block nca: Wt1 transpose + b23. Blocks nca+1..+5: W23.
__global__ __launch_bounds__(256) void passA_wt(const int* __restrict__ ei, int E,
        int* __restrict__ cntA, int nbkt, int nca,
        const float* __restrict__ W1, const float* __restrict__ W2,
        const float* __restrict__ W3, const float* __restrict__ b2,
        u16* __restrict__ Wt1, float* __restrict__ W23, float* __restrict__ b23) {
    int tid = threadIdx.x, b = blockIdx.x;
    if (b < nca) {
        __shared__ int h[256];
        h[tid] = 0;
        __syncthreads();
        int ch = (E + nca - 1) / nca;
        int beg = b * ch, end = min(beg + ch, E);
        for (int e = beg + tid; e < end; e += 256)
            atomicAdd(&h[ei[E + e] >> 8], 1);               // LDS atomic
        __syncthreads();
        if (tid < nbkt) cntA[tid * nca + b] = h[tid];       // all entries written
    } else if (b == nca) {
        for (int i = 0; i < 64; ++i) {
            int idx = tid + i * 256;          // 16384 = 128*128
            int k = idx >> 7, c = idx & 127;
            Wt1[c * 128 + k] = bf16_1(W1[idx]);
        }
        // b23[c] = sum_j b2[j]*W3[j][c]: 16 lanes per output.
        int c = tid >> 4, j0 = tid & 15;
        float acc = 0.f;
        if (c < 10) {
#pragma unroll
            for (int j = 0; j < 128; j += 16)
                acc += b2[j + j0] * W3[(j + j0) * 10 + c];
        }
#pragma unroll
        for (int m = 1; m < 16; m <<= 1) acc += __shfl_xor(acc, m);
        if (c < 10 && j0 == 0) b23[c] = acc;
    } else {
        // W23: one output per thread, idx = (b-nca-1)*256 + tid (5*256=1280).
        __shared__ float w3s[1280];
        for (int i = tid; i < 1280; i += 256) w3s[i] = W3[i];
        __syncthreads();
        int idx = (b - nca - 1) * 256 + tid;
        int k = idx / 10, c = idx % 10;
        const float* w2r = W2 + (size_t)k * 128;
        float a0 = 0.f, a1 = 0.f, a2 = 0.f, a3 = 0.f;
#pragma unroll
        for (int j = 0; j < 128; j += 4) {
            a0 += w2r[j + 0] * w3s[(j + 0) * 10 + c];
            a1 += w2r[j + 1] * w3s[(j + 1) * 10 + c];
            a2 += w2r[j + 2] * w3s[(j + 2) * 10 + c];
            a3 += w2r[j + 3] * w3s[(j + 3) * 10 + c];
        }
        W23[idx] = (a0 + a1) + (a2 + a3);
    }
}

// Per-bucket exclusive scan over the nca block counts; total -> btot[bucket].
__global__ __launch_bounds__(256) void scan1(int* __restrict__ cntA, int nca,
        int* __restrict__ btot) {
    __shared__ int s[256];
    int b = blockIdx.x, tid = threadIdx.x;   // b = bucket; tid = chunk-block
    int v = cntA[b * nca + tid];
    s[tid] = v;
    __syncthreads();
    for (int d = 1; d < 256; d <<= 1) {
        int t = (tid >= d) ? s[tid - d] : 0;
        __syncthreads();
        s[tid] += t;
        __syncthreads();
    }
    cntA[b * nca + tid] = s[tid] - v;        // exclusive within bucket
    if (tid == 255) btot[b] = s[255];
}

// Scatter edges into bucket-contiguous ebkt via LDS cursors.
// Bucket bases derived by redundant LDS scan of btot (no scan2 kernel).
__global__ __launch_bounds__(256) void passB(const int* __restrict__ ei, int E,
        const int* __restrict__ cntA, int nca, int nbkt,
        const int* __restrict__ btot, int2e* __restrict__ ebkt) {
    __shared__ int sc[256];
    __shared__ int cur[256];
    int tid = threadIdx.x, b = blockIdx.x;
    int v = (tid < nbkt) ? btot[tid] : 0;
    sc[tid] = v;
    __syncthreads();
    for (int d = 1; d < 256; d <<= 1) {
        int t = (tid >= d) ? sc[tid - d] : 0;
        __syncthreads();
        sc[tid] += t;
        __syncthreads();
    }
    cur[tid] = (sc[tid] - v) + ((tid < nbkt) ? cntA[tid * nca + b] : 0);
    __syncthreads();
    int ch = (E + nca - 1) / nca;
    int beg = b * ch, end = min(beg + ch, E);
    for (int e = beg + tid; e < end; e += 256) {
        int s = ei[e], d = ei[E + e];
        int pos = atomicAdd(&cur[d >> 8], 1);               // LDS atomic
        int2e pkt;
        pkt.x = s;
        pkt.y = d;
        ebkt[pos] = pkt;
    }
}

// Per-bucket fine counting sort: deg/dis/row_ptr + dst-sorted esort (src,dst).
// Bucket base via redundant LDS scan of btot.
__global__ __launch_bounds__(256) void passC(const int2e* __restrict__ ebkt,
        const int* __restrict__ btot, int2e* __restrict__ esort,
        int* __restrict__ row_ptr, float* __restrict__ dis, int n, int nbkt, int E) {
    __shared__ int sc[256];
    __shared__ int fc[256];
    __shared__ int s_base;
    int k = blockIdx.x, tid = threadIdx.x;
    int bt = (tid < nbkt) ? btot[tid] : 0;
    sc[tid] = bt;
    __syncthreads();
    for (int d = 1; d < 256; d <<= 1) {
        int t = (tid >= d) ? sc[tid - d] : 0;
        __syncthreads();
        sc[tid] += t;
        __syncthreads();
    }
    if (tid == k) s_base = sc[tid] - bt;                    // excl base of bucket k
    fc[tid] = 0;
    __syncthreads();
    int base = s_base;
    int endb = base + btot[k];
    int node0 = k << 8;
    for (int i = base + tid; i < endb; i += 256)
        atomicAdd(&fc[ebkt[i].y & 255], 1);                 // LDS atomic
    __syncthreads();
    int v = fc[tid];
    sc[tid] = v;
    __syncthreads();
    for (int d = 1; d < 256; d <<= 1) {
        int t = (tid >= d) ? sc[tid - d] : 0;
        __syncthreads();
        sc[tid] += t;
        __syncthreads();
    }
    int excl = sc[tid] - v;
    if (node0 + tid < n) {
        dis[node0 + tid] = rsqrtf((float)(v + 1));          // +1 self-loop
        row_ptr[node0 + tid] = base + excl;
    }
    __syncthreads();
    fc[tid] = base + excl;                                  // reuse as cursor
    __syncthreads();
    for (int i = base + tid; i < endb; i += 256) {
        int2e ed = ebkt[i];
        int pos = atomicAdd(&fc[ed.y & 255], 1);            // LDS atomic
        esort[pos] = ed;                                    // (src, dst)
    }
    if (k == 0 && tid == 0) row_ptr[n] = E;
}

// out u16[n][128] = bf16( A[n][128] @ W ),  W given as Wt bf16 [col][k].
__global__ __launch_bounds__(256) void gemm_mfma(const float* __restrict__ A,
        const u16* __restrict__ Wt, u16* __restrict__ out, int n) {
    constexpr int LDA = 136;                 // 128 + 8 pad (bf16) -> 2-way LDS only
    __shared__ u16 as[64 * LDA];
    int tid = threadIdx.x;
    int wave = tid >> 6, lane = tid & 63;
    int row0 = blockIdx.x * 64;
    int l16 = lane & 15;
    int krow = (lane >> 4) * 8;              // k-octet within 32-wide K block

#pragma unroll
    for (int i = 0; i < 8; ++i) {
        int idx = tid + i * 256;             // 2048 quads of 4 f32
        int r = idx >> 5;
        int q = (idx & 31) * 4;
        float4e v = {0.f, 0.f, 0.f, 0.f};
        if (row0 + r < n)
            v = *reinterpret_cast<const float4e*>(A + (size_t)(row0 + r) * 128 + q);
        uint2e p;
        p.x = pack_bf2(v.x, v.y);
        p.y = pack_bf2(v.z, v.w);
        *reinterpret_cast<uint2e*>(&as[r * LDA + q]) = p;
    }

    bf16x8 b[2][4];
#pragma unroll
    for (int n2 = 0; n2 < 2; ++n2)
#pragma unroll
        for (int kb = 0; kb < 4; ++kb)
            b[n2][kb] = *reinterpret_cast<const bf16x8*>(
                Wt + (size_t)(wave * 32 + n2 * 16 + l16) * 128 + kb * 32 + krow);

    __syncthreads();

    f32x4 acc[4][2] = {};
#pragma unroll
    for (int m = 0; m < 4; ++m) {
#pragma unroll
        for (int kb = 0; kb < 4; ++kb) {
            bf16x8 a = *reinterpret_cast<const bf16x8*>(
                &as[(m * 16 + l16) * LDA + kb * 32 + krow]);
#pragma unroll
            for (int n2 = 0; n2 < 2; ++n2)
                acc[m][n2] = __builtin_amdgcn_mfma_f32_16x16x32_bf16(a, b[n2][kb], acc[m][n2], 0, 0, 0);
        }
    }

    __syncthreads();                         // as[] reuse as C-staging
    u16* cs = as;
#pragma unroll
    for (int m = 0; m < 4; ++m) {
        int rb = m * 16 + (lane >> 4) * 4;
#pragma unroll
        for (int n2 = 0; n2 < 2; ++n2) {
            int col = wave * 32 + n2 * 16 + l16;
#pragma unroll
            for (int r = 0; r < 4; ++r)
                cs[(rb + r) * 128 + col] = bf16_1(acc[m][n2][r]);
        }
    }
    __syncthreads();
#pragma unroll
    for (int i = 0; i < 4; ++i) {
        int idx = tid + i * 256;             // 1024 octs: row=idx>>4, oct=(idx&15)
        int r = idx >> 4;
        int q = (idx & 15) * 8;
        if (row0 + r < n)
            *reinterpret_cast<uint4e*>(out + (size_t)(row0 + r) * 128 + q) =
                *reinterpret_cast<const uint4e*>(&cs[r * 128 + q]);
    }
}

// Full-wave gather with on-the-fly norm: esort = (src,dst); w = dis[s]*dis[v].
// Lane owns dims 2*lane..2*lane+1, 8 edges in flight.
__device__ __forceinline__ void gather_accum(const uint* __restrict__ xw,
        const int2e* __restrict__ esort, const float* __restrict__ dis,
        int v, int lane, int beg, int end, float& ax, float& ay) {
    float dv = dis[v];
    int e = beg;
    for (; e + 7 < end; e += 8) {
        int2e ed[8];
        uint vv[8];
        float wd[8];
#pragma unroll
        for (int j = 0; j < 8; ++j) ed[j] = esort[e + j];
#pragma unroll
        for (int j = 0; j < 8; ++j) {
            vv[j] = xw[(size_t)ed[j].x * 64 + lane];
            wd[j] = dis[ed[j].x];
        }
#pragma unroll
        for (int j = 0; j < 8; ++j) {
            float w = wd[j] * dv;
            ax += w * bf_lo(vv[j]);
            ay += w * bf_hi(vv[j]);
        }
    }
    for (; e + 1 < end; e += 2) {
        int2e e0 = esort[e];
        int2e e1 = esort[e + 1];
        uint v0 = xw[(size_t)e0.x * 64 + lane];
        uint v1 = xw[(size_t)e1.x * 64 + lane];
        float w0 = dis[e0.x] * dv, w1 = dis[e1.x] * dv;
        ax += w0 * bf_lo(v0); ay += w0 * bf_hi(v0);
        ax += w1 * bf_lo(v1); ay += w1 * bf_hi(v1);
    }
    if (e < end) {
        int2e e0 = esort[e];
        uint v0 = xw[(size_t)e0.x * 64 + lane];
        float w0 = dis[e0.x] * dv;
        ax += w0 * bf_lo(v0); ay += w0 * bf_hi(v0);
    }
    float wv = dv * dv;                            // self-loop norm
    uint vs = xw[(size_t)v * 64 + lane];
    ax += wv * bf_lo(vs); ay += wv * bf_hi(vs);
}

// Pass A: z[v][0..9] = relu(Agg(x@W1)[v] + b1) @ W23   (the one big gather).
__global__ __launch_bounds__(256) void agg_proj_kernel(const uint* __restrict__ xw,
        const int* __restrict__ row_ptr, const int2e* __restrict__ esort,
        const float* __restrict__ dis, const float* __restrict__ b1,
        const float* __restrict__ W23, float* __restrict__ z, int n) {
    int v = (int)((blockIdx.x * blockDim.x + threadIdx.x) >> 6);
    int lane = threadIdx.x & 63;
    if (v >= n) return;
    float ax = 0.f, ay = 0.f;
    gather_accum(xw, esort, dis, v, lane, row_ptr[v], row_ptr[v + 1], ax, ay);
    ax = fmaxf(ax + b1[lane * 2], 0.f);
    ay = fmaxf(ay + b1[lane * 2 + 1], 0.f);
    const float* w0 = W23 + (size_t)lane * 20;     // this lane's 2 rows of W23
    float p[10];
#pragma unroll
    for (int c = 0; c < 10; ++c) p[c] = ax * w0[c] + ay * w0[10 + c];
#pragma unroll
    for (int c = 0; c < 10; ++c) {
#pragma unroll
        for (int d = 1; d < 64; d <<= 1) p[c] += __shfl_xor(p[c], d);
    }
    if (lane < 10) z[(size_t)v * 10 + lane] = p[lane];
}

// Pass B/C: 10-dim aggregation, 4 nodes per wave (16-lane groups).
// FINAL=0: zout = Agg(zin).  FINAL=1: log_softmax(Agg(zin) + s*b23 + b3).
// esort = (src,dst); w computed on the fly.
template <int FINAL>
__global__ __launch_bounds__(256) void agg10_kernel(const float* __restrict__ zin,
        const int* __restrict__ row_ptr, const int2e* __restrict__ esort,
        const float* __restrict__ dis, const float* __restrict__ b23,
        const float* __restrict__ b3, float* __restrict__ zout, int n) {
    int wid = (int)((blockIdx.x * blockDim.x + threadIdx.x) >> 6);
    int lane = threadIdx.x & 63;
    int grp = lane >> 4, gl = lane & 15;
    int v = wid * 4 + grp;
    bool act = (v < n);
    bool dl = (gl < 10);
    int beg = act ? row_ptr[v] : 0;
    int end = act ? row_ptr[v + 1] : 0;
    float dv = act ? dis[v] : 0.f;
    float acc = 0.f, sw = 0.f;
    int e = beg;
    for (; e + 3 < end; e += 4) {
        int2e e0 = esort[e], e1 = esort[e + 1], e2 = esort[e + 2], e3 = esort[e + 3];
        float z0 = dl ? zin[(size_t)e0.x * 10 + gl] : 0.f;
        float z1 = dl ? zin[(size_t)e1.x * 10 + gl] : 0.f;
        float z2 = dl ? zin[(size_t)e2.x * 10 + gl] : 0.f;
        float z3 = dl ? zin[(size_t)e3.x * 10 + gl] : 0.f;
        float w0 = dis[e0.x] * dv, w1 = dis[e1.x] * dv;
        float w2 = dis[e2.x] * dv, w3 = dis[e3.x] * dv;
        acc += w0 * z0 + w1 * z1 + w2 * z2 + w3 * z3;
        sw += (w0 + w1) + (w2 + w3);
    }
    for (; e < end; ++e) {
        int2e e0 = esort[e];
        float z0 = dl ? zin[(size_t)e0.x * 10 + gl] : 0.f;
        float w0 = dis[e0.x] * dv;
        acc += w0 * z0;
        sw += w0;
    }
    if (act) {
        float wv = dv * dv;                        // self-loop
        float zs = dl ? zin[(size_t)v * 10 + gl] : 0.f;
        acc += wv * zs;
        sw += wv;
    }
    if (FINAL == 0) {
        if (act && dl) zout[(size_t)v * 10 + gl] = acc;
    } else {
        float p = acc + (dl ? sw * b23[gl] + b3[gl] : 0.f);
        float m = dl ? p : -3.4e38f;
#pragma unroll
        for (int mask = 1; mask < 16; mask <<= 1) m = fmaxf(m, __shfl_xor(m, mask));
        float s = dl ? __expf(p - m) : 0.f;
#pragma unroll
        for (int mask = 1; mask < 16; mask <<= 1) s += __shfl_xor(s, mask);
        float ls = __logf(s);
        if (act && dl) zout[(size_t)v * 10 + gl] = p - m - ls;
    }
}

extern "C" void kernel_launch(void* const* d_in, const int* in_sizes, int n_in,
                              void* d_out, int out_size, void* d_ws, size_t ws_size,
                              hipStream_t stream) {
    const float* x  = (const float*)d_in[0];
    const int*   ei = (const int*)d_in[1];   // [2][E] int32
    const float* W1 = (const float*)d_in[2];
    const float* b1 = (const float*)d_in[3];
    const float* W2 = (const float*)d_in[4];
    const float* b2 = (const float*)d_in[5];
    const float* W3 = (const float*)d_in[6];
    const float* b3 = (const float*)d_in[7];
    int N = in_sizes[0] / 128;
    int E = in_sizes[1] / 2;
    int NBKT = (N + 255) >> 8;    // 196 for N=50000 (must be <= 256)
    const int NCA = 256;          // chunk blocks for passes A/B

    char* ws = (char*)d_ws;
    size_t off = 0;
    auto alloc = [&](size_t bytes) -> char* {
        char* p = ws + off;
        off = (off + bytes + 255) & ~(size_t)255;
        return p;
    };
    int*   cntA    = (int*)alloc((size_t)NBKT * NCA * 4);  // (bucket x block) counts
    int*   btot    = (int*)alloc(256 * 4);
    int*   row_ptr = (int*)alloc(((size_t)N + 1) * 4);
    float* dis     = (float*)alloc((size_t)N * 4);
    u16*   Wt1     = (u16*)alloc(128 * 128 * 2);
    float* W23     = (float*)alloc(128 * 10 * 4);
    float* b23     = (float*)alloc(10 * 4);
    int2e* ebkt    = (int2e*)alloc((size_t)E * 8);         // bucket-sorted (src,dst)
    int2e* esort   = (int2e*)alloc((size_t)E * 8);         // dst-sorted (src,dst)
    uint*  bufA    = (uint*)alloc((size_t)N * 64 * 4);     // bf16x2 packed x@W1
    float* z       = (float*)alloc((size_t)N * 10 * 4);    // h1@W23 (2MB, L2-fits)
    float* z2      = (float*)alloc((size_t)N * 10 * 4);    // Agg(z)

    // --- preprocessing: LDS-atomic counting sort + weight prep (no memset) ---
    passA_wt<<<NCA + 6, 256, 0, stream>>>(ei, E, cntA, NBKT, NCA, W1, W2, W3, b2,
                                          Wt1, W23, b23);
    // layer-1 GEMM (needs Wt1 from passA_wt)
    gemm_mfma<<<(N + 63) / 64, 256, 0, stream>>>(x, Wt1, (u16*)bufA, N);
    scan1<<<NBKT, 256, 0, stream>>>(cntA, NCA, btot);
    passB<<<NCA, 256, 0, stream>>>(ei, E, cntA, NCA, NBKT, btot, ebkt);
    passC<<<NBKT, 256, 0, stream>>>(ebkt, btot, esort, row_ptr, dis, N, NBKT, E);
    // --- the single 128-dim gather, fused with ReLU+projection ---
    agg_proj_kernel<<<(N + 3) / 4, 256, 0, stream>>>(bufA, row_ptr, esort, dis, b1, W23, z, N);
    // --- layers 2+3: two 10-dim aggregations (L2-resident table) ---
    agg10_kernel<0><<<(N + 15) / 16, 256, 0, stream>>>(z, row_ptr, esort, dis, nullptr, nullptr, z2, N);
    agg10_kernel<1><<<(N + 15) / 16, 256, 0, stream>>>(z2, row_ptr, esort, dis, b23, b3, (float*)d_out, N);
}

// Round 17
// 129.543 us; speedup vs baseline: 1.5176x; 1.0446x over previous
//
#include <hip/hip_runtime.h>
#include <cstdint>
#include <cstddef>

// ---------------------------------------------------------------------------
// GCN: 3 layers, shared graph.
//   - Algebra: only layer 1 has ReLU; projection commutes with aggregation:
//       out = log_softmax( A^2 (relu(A xW1 + b1) W23) + s*(b2W3) + b3 ).
//     One 128-dim gather (compulsory L2-fill floor: 82MB @ ~1.7TB/s = 48us,
//     invariant R7-R16), then 10-dim space (L2-resident).
//   - R14/R15: device-scope global atomics write through (~32B/op); the
//     LDS-atomic two-level counting sort removed ~46us of atomic tax.
//   - R17: z/z2 tables packed bf16 (5xu32 = 20B/node, was 40B f32): halves
//     the 10-dim passes' per-XCD compulsory fill (16->8MB) and line count.
//     f32 accumulation throughout; two extra bf16 roundings fit the budget.
//   - R11 lesson: don't fuse kernels with opposite resource profiles.
//   - GEMM1: bf16 MFMA 16x16x32, C via LDS round-trip (16B stores).
// ---------------------------------------------------------------------------

typedef unsigned int uint;
typedef unsigned short u16;
typedef uint  uint4e  __attribute__((ext_vector_type(4)));
typedef float float4e __attribute__((ext_vector_type(4)));
typedef float float2e __attribute__((ext_vector_type(2)));
typedef uint  uint2e  __attribute__((ext_vector_type(2)));
typedef int   int2e   __attribute__((ext_vector_type(2)));
typedef int   int4e   __attribute__((ext_vector_type(4)));
using bf16x8 = __attribute__((ext_vector_type(8))) short;
using f32x4  = __attribute__((ext_vector_type(4))) float;

__device__ __forceinline__ float bf_lo(uint v) { return __uint_as_float(v << 16); }
__device__ __forceinline__ float bf_hi(uint v) { return __uint_as_float(v & 0xffff0000u); }
__device__ __forceinline__ u16 bf16_1(float a) {
    uint ua = __float_as_uint(a);
    ua = (ua + 0x7fffu + ((ua >> 16) & 1u)) >> 16;          // RNE
    return (u16)ua;
}
__device__ __forceinline__ uint pack_bf2(float a, float b) {
    return (uint)bf16_1(a) | ((uint)bf16_1(b) << 16);
}

// Blocks [0,nca): coarse histogram of dst buckets (dst>>8) in LDS ->
// cntA[bucket*nca + block]. Block nca: Wt1 transpose + b23. Blocks nca+1..+5: W23.
__global__ __launch_bounds__(256) void passA_wt(const int* __restrict__ ei, int E,
        int* __restrict__ cntA, int nbkt, int nca,
        const float* __restrict__ W1, const float* __restrict__ W2,
        const float* __restrict__ W3, const float* __restrict__ b2,
        u16* __restrict__ Wt1, float* __restrict__ W23, float* __restrict__ b23) {
    int tid = threadIdx.x, b = blockIdx.x;
    if (b < nca) {
        __shared__ int h[256];
        h[tid] = 0;
        __syncthreads();
        int ch = (E + nca - 1) / nca;
        int beg = b * ch, end = min(beg + ch, E);
        for (int e = beg + tid; e < end; e += 256)
            atomicAdd(&h[ei[E + e] >> 8], 1);               // LDS atomic
        __syncthreads();
        if (tid < nbkt) cntA[tid * nca + b] = h[tid];       // all entries written
    } else if (b == nca) {
        for (int i = 0; i < 64; ++i) {
            int idx = tid + i * 256;          // 16384 = 128*128
            int k = idx >> 7, c = idx & 127;
            Wt1[c * 128 + k] = bf16_1(W1[idx]);
        }
        // b23[c] = sum_j b2[j]*W3[j][c]: 16 lanes per output.
        int c = tid >> 4, j0 = tid & 15;
        float acc = 0.f;
        if (c < 10) {
#pragma unroll
            for (int j = 0; j < 128; j += 16)
                acc += b2[j + j0] * W3[(j + j0) * 10 + c];
        }
#pragma unroll
        for (int m = 1; m < 16; m <<= 1) acc += __shfl_xor(acc, m);
        if (c < 10 && j0 == 0) b23[c] = acc;
    } else {
        // W23: one output per thread, idx = (b-nca-1)*256 + tid (5*256=1280).
        __shared__ float w3s[1280];
        for (int i = tid; i < 1280; i += 256) w3s[i] = W3[i];
        __syncthreads();
        int idx = (b - nca - 1) * 256 + tid;
        int k = idx / 10, c = idx % 10;
        const float* w2r = W2 + (size_t)k * 128;
        float a0 = 0.f, a1 = 0.f, a2 = 0.f, a3 = 0.f;
#pragma unroll
        for (int j = 0; j < 128; j += 4) {
            a0 += w2r[j + 0] * w3s[(j + 0) * 10 + c];
            a1 += w2r[j + 1] * w3s[(j + 1) * 10 + c];
            a2 += w2r[j + 2] * w3s[(j + 2) * 10 + c];
            a3 += w2r[j + 3] * w3s[(j + 3) * 10 + c];
        }
        W23[idx] = (a0 + a1) + (a2 + a3);
    }
}

// Per-bucket exclusive scan over the nca block counts; total -> btot[bucket].
__global__ __launch_bounds__(256) void scan1(int* __restrict__ cntA, int nca,
        int* __restrict__ btot) {
    __shared__ int s[256];
    int b = blockIdx.x, tid = threadIdx.x;   // b = bucket; tid = chunk-block
    int v = cntA[b * nca + tid];
    s[tid] = v;
    __syncthreads();
    for (int d = 1; d < 256; d <<= 1) {
        int t = (tid >= d) ? s[tid - d] : 0;
        __syncthreads();
        s[tid] += t;
        __syncthreads();
    }
    cntA[b * nca + tid] = s[tid] - v;        // exclusive within bucket
    if (tid == 255) btot[b] = s[255];
}

// Scatter edges into bucket-contiguous ebkt via LDS cursors.
// Bucket bases derived by redundant LDS scan of btot (no scan2 kernel).
__global__ __launch_bounds__(256) void passB(const int* __restrict__ ei, int E,
        const int* __restrict__ cntA, int nca, int nbkt,
        const int* __restrict__ btot, int2e* __restrict__ ebkt) {
    __shared__ int sc[256];
    __shared__ int cur[256];
    int tid = threadIdx.x, b = blockIdx.x;
    int v = (tid < nbkt) ? btot[tid] : 0;
    sc[tid] = v;
    __syncthreads();
    for (int d = 1; d < 256; d <<= 1) {
        int t = (tid >= d) ? sc[tid - d] : 0;
        __syncthreads();
        sc[tid] += t;
        __syncthreads();
    }
    cur[tid] = (sc[tid] - v) + ((tid < nbkt) ? cntA[tid * nca + b] : 0);
    __syncthreads();
    int ch = (E + nca - 1) / nca;
    int beg = b * ch, end = min(beg + ch, E);
    for (int e = beg + tid; e < end; e += 256) {
        int s = ei[e], d = ei[E + e];
        int pos = atomicAdd(&cur[d >> 8], 1);               // LDS atomic
        int2e pkt;
        pkt.x = s;
        pkt.y = d;
        ebkt[pos] = pkt;
    }
}

// Per-bucket fine counting sort: deg/dis/row_ptr + dst-sorted esort (src,dst).
// Bucket base via redundant LDS scan of btot.
__global__ __launch_bounds__(256) void passC(const int2e* __restrict__ ebkt,
        const int* __restrict__ btot, int2e* __restrict__ esort,
        int* __restrict__ row_ptr, float* __restrict__ dis, int n, int nbkt, int E) {
    __shared__ int sc[256];
    __shared__ int fc[256];
    __shared__ int s_base;
    int k = blockIdx.x, tid = threadIdx.x;
    int bt = (tid < nbkt) ? btot[tid] : 0;
    sc[tid] = bt;
    __syncthreads();
    for (int d = 1; d < 256; d <<= 1) {
        int t = (tid >= d) ? sc[tid - d] : 0;
        __syncthreads();
        sc[tid] += t;
        __syncthreads();
    }
    if (tid == k) s_base = sc[tid] - bt;                    // excl base of bucket k
    fc[tid] = 0;
    __syncthreads();
    int base = s_base;
    int endb = base + btot[k];
    int node0 = k << 8;
    for (int i = base + tid; i < endb; i += 256)
        atomicAdd(&fc[ebkt[i].y & 255], 1);                 // LDS atomic
    __syncthreads();
    int v = fc[tid];
    sc[tid] = v;
    __syncthreads();
    for (int d = 1; d < 256; d <<= 1) {
        int t = (tid >= d) ? sc[tid - d] : 0;
        __syncthreads();
        sc[tid] += t;
        __syncthreads();
    }
    int excl = sc[tid] - v;
    if (node0 + tid < n) {
        dis[node0 + tid] = rsqrtf((float)(v + 1));          // +1 self-loop
        row_ptr[node0 + tid] = base + excl;
    }
    __syncthreads();
    fc[tid] = base + excl;                                  // reuse as cursor
    __syncthreads();
    for (int i = base + tid; i < endb; i += 256) {
        int2e ed = ebkt[i];
        int pos = atomicAdd(&fc[ed.y & 255], 1);            // LDS atomic
        esort[pos] = ed;                                    // (src, dst)
    }
    if (k == 0 && tid == 0) row_ptr[n] = E;
}

// out u16[n][128] = bf16( A[n][128] @ W ),  W given as Wt bf16 [col][k].
__global__ __launch_bounds__(256) void gemm_mfma(const float* __restrict__ A,
        const u16* __restrict__ Wt, u16* __restrict__ out, int n) {
    constexpr int LDA = 136;                 // 128 + 8 pad (bf16) -> 2-way LDS only
    __shared__ u16 as[64 * LDA];
    int tid = threadIdx.x;
    int wave = tid >> 6, lane = tid & 63;
    int row0 = blockIdx.x * 64;
    int l16 = lane & 15;
    int krow = (lane >> 4) * 8;              // k-octet within 32-wide K block

#pragma unroll
    for (int i = 0; i < 8; ++i) {
        int idx = tid + i * 256;             // 2048 quads of 4 f32
        int r = idx >> 5;
        int q = (idx & 31) * 4;
        float4e v = {0.f, 0.f, 0.f, 0.f};
        if (row0 + r < n)
            v = *reinterpret_cast<const float4e*>(A + (size_t)(row0 + r) * 128 + q);
        uint2e p;
        p.x = pack_bf2(v.x, v.y);
        p.y = pack_bf2(v.z, v.w);
        *reinterpret_cast<uint2e*>(&as[r * LDA + q]) = p;
    }

    bf16x8 b[2][4];
#pragma unroll
    for (int n2 = 0; n2 < 2; ++n2)
#pragma unroll
        for (int kb = 0; kb < 4; ++kb)
            b[n2][kb] = *reinterpret_cast<const bf16x8*>(
                Wt + (size_t)(wave * 32 + n2 * 16 + l16) * 128 + kb * 32 + krow);

    __syncthreads();

    f32x4 acc[4][2] = {};
#pragma unroll
    for (int m = 0; m < 4; ++m) {
#pragma unroll
        for (int kb = 0; kb < 4; ++kb) {
            bf16x8 a = *reinterpret_cast<const bf16x8*>(
                &as[(m * 16 + l16) * LDA + kb * 32 + krow]);
#pragma unroll
            for (int n2 = 0; n2 < 2; ++n2)
                acc[m][n2] = __builtin_amdgcn_mfma_f32_16x16x32_bf16(a, b[n2][kb], acc[m][n2], 0, 0, 0);
        }
    }

    __syncthreads();                         // as[] reuse as C-staging
    u16* cs = as;
#pragma unroll
    for (int m = 0; m < 4; ++m) {
        int rb = m * 16 + (lane >> 4) * 4;
#pragma unroll
        for (int n2 = 0; n2 < 2; ++n2) {
            int col = wave * 32 + n2 * 16 + l16;
#pragma unroll
            for (int r = 0; r < 4; ++r)
                cs[(rb + r) * 128 + col] = bf16_1(acc[m][n2][r]);
        }
    }
    __syncthreads();
#pragma unroll
    for (int i = 0; i < 4; ++i) {
        int idx = tid + i * 256;             // 1024 octs: row=idx>>4, oct=(idx&15)
        int r = idx >> 4;
        int q = (idx & 15) * 8;
        if (row0 + r < n)
            *reinterpret_cast<uint4e*>(out + (size_t)(row0 + r) * 128 + q) =
                *reinterpret_cast<const uint4e*>(&cs[r * 128 + q]);
    }
}

// Full-wave gather with on-the-fly norm: esort = (src,dst); w = dis[s]*dis[v].
// Lane owns dims 2*lane..2*lane+1, 8 edges in flight.
__device__ __forceinline__ void gather_accum(const uint* __restrict__ xw,
        const int2e* __restrict__ esort, const float* __restrict__ dis,
        int v, int lane, int beg, int end, float& ax, float& ay) {
    float dv = dis[v];
    int e = beg;
    for (; e + 7 < end; e += 8) {
        int2e ed[8];
        uint vv[8];
        float wd[8];
#pragma unroll
        for (int j = 0; j < 8; ++j) ed[j] = esort[e + j];
#pragma unroll
        for (int j = 0; j < 8; ++j) {
            vv[j] = xw[(size_t)ed[j].x * 64 + lane];
            wd[j] = dis[ed[j].x];
        }
#pragma unroll
        for (int j = 0; j < 8; ++j) {
            float w = wd[j] * dv;
            ax += w * bf_lo(vv[j]);
            ay += w * bf_hi(vv[j]);
        }
    }
    for (; e + 1 < end; e += 2) {
        int2e e0 = esort[e];
        int2e e1 = esort[e + 1];
        uint v0 = xw[(size_t)e0.x * 64 + lane];
        uint v1 = xw[(size_t)e1.x * 64 + lane];
        float w0 = dis[e0.x] * dv, w1 = dis[e1.x] * dv;
        ax += w0 * bf_lo(v0); ay += w0 * bf_hi(v0);
        ax += w1 * bf_lo(v1); ay += w1 * bf_hi(v1);
    }
    if (e < end) {
        int2e e0 = esort[e];
        uint v0 = xw[(size_t)e0.x * 64 + lane];
        float w0 = dis[e0.x] * dv;
        ax += w0 * bf_lo(v0); ay += w0 * bf_hi(v0);
    }
    float wv = dv * dv;                            // self-loop norm
    uint vs = xw[(size_t)v * 64 + lane];
    ax += wv * bf_lo(vs); ay += wv * bf_hi(vs);
}

// Pass A: z[v] = packed bf16 of relu(Agg(x@W1)[v] + b1) @ W23  (5 x u32/node).
__global__ __launch_bounds__(256) void agg_proj_kernel(const uint* __restrict__ xw,
        const int* __restrict__ row_ptr, const int2e* __restrict__ esort,
        const float* __restrict__ dis, const float* __restrict__ b1,
        const float* __restrict__ W23, uint* __restrict__ z, int n) {
    int v = (int)((blockIdx.x * blockDim.x + threadIdx.x) >> 6);
    int lane = threadIdx.x & 63;
    if (v >= n) return;
    float ax = 0.f, ay = 0.f;
    gather_accum(xw, esort, dis, v, lane, row_ptr[v], row_ptr[v + 1], ax, ay);
    ax = fmaxf(ax + b1[lane * 2], 0.f);
    ay = fmaxf(ay + b1[lane * 2 + 1], 0.f);
    const float* w0 = W23 + (size_t)lane * 20;     // this lane's 2 rows of W23
    float p[10];
#pragma unroll
    for (int c = 0; c < 10; ++c) p[c] = ax * w0[c] + ay * w0[10 + c];
#pragma unroll
    for (int c = 0; c < 10; ++c) {
#pragma unroll
        for (int d = 1; d < 64; d <<= 1) p[c] += __shfl_xor(p[c], d);
    }
    if (lane < 5) z[(size_t)v * 5 + lane] = pack_bf2(p[2 * lane], p[2 * lane + 1]);
}

// Pass B/C: 10-dim aggregation over packed-bf16 z. 4 nodes per wave (16-lane
// groups); lanes 0-4 of each group own dims (2gl, 2gl+1). 8 edges in flight.
// FINAL=0: zout(packed) = Agg(zin).
// FINAL=1: out(f32) = log_softmax(Agg(zin) + s*b23 + b3).
template <int FINAL>
__global__ __launch_bounds__(256) void agg10_kernel(const uint* __restrict__ zin,
        const int* __restrict__ row_ptr, const int2e* __restrict__ esort,
        const float* __restrict__ dis, const float* __restrict__ b23,
        const float* __restrict__ b3, void* __restrict__ zout, int n) {
    int wid = (int)((blockIdx.x * blockDim.x + threadIdx.x) >> 6);
    int lane = threadIdx.x & 63;
    int grp = lane >> 4, gl = lane & 15;
    int v = wid * 4 + grp;
    bool act = (v < n);
    bool dl = (gl < 5);
    int beg = act ? row_ptr[v] : 0;
    int end = act ? row_ptr[v + 1] : 0;
    float dv = act ? dis[v] : 0.f;
    float ax = 0.f, ay = 0.f, sw = 0.f;
    int e = beg;
    for (; e + 7 < end; e += 8) {
        int2e ed[8];
        uint zz[8];
        float wd[8];
#pragma unroll
        for (int j = 0; j < 8; ++j) ed[j] = esort[e + j];
#pragma unroll
        for (int j = 0; j < 8; ++j) {
            zz[j] = dl ? zin[(size_t)ed[j].x * 5 + gl] : 0u;
            wd[j] = dis[ed[j].x];
        }
#pragma unroll
        for (int j = 0; j < 8; ++j) {
            float w = wd[j] * dv;
            ax += w * bf_lo(zz[j]);
            ay += w * bf_hi(zz[j]);
            sw += w;
        }
    }
    for (; e < end; ++e) {
        int2e e0 = esort[e];
        uint z0 = dl ? zin[(size_t)e0.x * 5 + gl] : 0u;
        float w0 = dis[e0.x] * dv;
        ax += w0 * bf_lo(z0);
        ay += w0 * bf_hi(z0);
        sw += w0;
    }
    if (act) {
        float wv = dv * dv;                        // self-loop
        uint zs = dl ? zin[(size_t)v * 5 + gl] : 0u;
        ax += wv * bf_lo(zs);
        ay += wv * bf_hi(zs);
        sw += wv;
    }
    if (FINAL == 0) {
        if (act && dl) ((uint*)zout)[(size_t)v * 5 + gl] = pack_bf2(ax, ay);
    } else {
        float pa = 0.f, pb = 0.f;
        if (dl) {
            pa = ax + sw * b23[2 * gl] + b3[2 * gl];
            pb = ay + sw * b23[2 * gl + 1] + b3[2 * gl + 1];
        }
        float m = dl ? fmaxf(pa, pb) : -3.4e38f;
#pragma unroll
        for (int mask = 1; mask < 16; mask <<= 1) m = fmaxf(m, __shfl_xor(m, mask));
        float s = dl ? (__expf(pa - m) + __expf(pb - m)) : 0.f;
#pragma unroll
        for (int mask = 1; mask < 16; mask <<= 1) s += __shfl_xor(s, mask);
        float ls = __logf(s);
        if (act && dl) {
            float2e o = {pa - m - ls, pb - m - ls};
            *reinterpret_cast<float2e*>((float*)zout + (size_t)v * 10 + 2 * gl) = o;
        }
    }
}

extern "C" void kernel_launch(void* const* d_in, const int* in_sizes, int n_in,
                              void* d_out, int out_size, void* d_ws, size_t ws_size,
                              hipStream_t stream) {
    const float* x  = (const float*)d_in[0];
    const int*   ei = (const int*)d_in[1];   // [2][E] int32
    const float* W1 = (const float*)d_in[2];
    const float* b1 = (const float*)d_in[3];
    const float* W2 = (const float*)d_in[4];
    const float* b2 = (const float*)d_in[5];
    const float* W3 = (const float*)d_in[6];
    const float* b3 = (const float*)d_in[7];
    int N = in_sizes[0] / 128;
    int E = in_sizes[1] / 2;
    int NBKT = (N + 255) >> 8;    // 196 for N=50000 (must be <= 256)
    const int NCA = 256;          // chunk blocks for passes A/B

    char* ws = (char*)d_ws;
    size_t off = 0;
    auto alloc = [&](size_t bytes) -> char* {
        char* p = ws + off;
        off = (off + bytes + 255) & ~(size_t)255;
        return p;
    };
    int*   cntA    = (int*)alloc((size_t)NBKT * NCA * 4);  // (bucket x block) counts
    int*   btot    = (int*)alloc(256 * 4);
    int*   row_ptr = (int*)alloc(((size_t)N + 1) * 4);
    float* dis     = (float*)alloc((size_t)N * 4);
    u16*   Wt1     = (u16*)alloc(128 * 128 * 2);
    float* W23     = (float*)alloc(128 * 10 * 4);
    float* b23     = (float*)alloc(10 * 4);
    int2e* ebkt    = (int2e*)alloc((size_t)E * 8);         // bucket-sorted (src,dst)
    int2e* esort   = (int2e*)alloc((size_t)E * 8);         // dst-sorted (src,dst)
    uint*  bufA    = (uint*)alloc((size_t)N * 64 * 4);     // bf16x2 packed x@W1
    uint*  z       = (uint*)alloc((size_t)N * 5 * 4);      // packed bf16 h1@W23 (1MB)
    uint*  z2      = (uint*)alloc((size_t)N * 5 * 4);      // packed bf16 Agg(z)

    // --- preprocessing: LDS-atomic counting sort + weight prep (no memset) ---
    passA_wt<<<NCA + 6, 256, 0, stream>>>(ei, E, cntA, NBKT, NCA, W1, W2, W3, b2,
                                          Wt1, W23, b23);
    // layer-1 GEMM (needs Wt1 from passA_wt)
    gemm_mfma<<<(N + 63) / 64, 256, 0, stream>>>(x, Wt1, (u16*)bufA, N);
    scan1<<<NBKT, 256, 0, stream>>>(cntA, NCA, btot);
    passB<<<NCA, 256, 0, stream>>>(ei, E, cntA, NCA, NBKT, btot, ebkt);
    passC<<<NBKT, 256, 0, stream>>>(ebkt, btot, esort, row_ptr, dis, N, NBKT, E);
    // --- the single 128-dim gather, fused with ReLU+projection ---
    agg_proj_kernel<<<(N + 3) / 4, 256, 0, stream>>>(bufA, row_ptr, esort, dis, b1, W23, z, N);
    // --- layers 2+3: two 10-dim aggregations (packed bf16, L2-resident) ---
    agg10_kernel<0><<<(N + 15) / 16, 256, 0, stream>>>(z, row_ptr, esort, dis, nullptr, nullptr, z2, N);
    agg10_kernel<1><<<(N + 15) / 16, 256, 0, stream>>>(z2, row_ptr, esort, dis, b23, b3, d_out, N);
}